// Round 7
// baseline (175.854 us; speedup 1.0000x reference)
//
#include <hip/hip_runtime.h>
#include <hip/hip_bf16.h>

#define B_ 8
#define N_ 8192
#define D_ 512
#define M_ 64

typedef unsigned short u16;
typedef unsigned int u32;
typedef __attribute__((ext_vector_type(8))) short bf16x8;
typedef __attribute__((ext_vector_type(4))) float f32x4;

__device__ __forceinline__ u16 f2bf(float f) {
  u32 u = __float_as_uint(f);
  u += 0x7FFFu + ((u >> 16) & 1u);
  return (u16)(u >> 16);
}
__device__ __forceinline__ float bf2f(u16 h) {
  return __uint_as_float(((u32)h) << 16);
}

// B-fragment index for matrix Mx[kd][c] with N cols: slot mapping shared by A.
__device__ __forceinline__ int bfrag_idx(int kd, int c, int ncols16) {
  int sub = (kd >> 5) * ncols16 + (c >> 4);
  int lane = (c & 15) + 16 * ((kd & 15) >> 2);
  int e = (kd & 3) + 4 * ((kd >> 4) & 1);
  return sub * 512 + lane * 8 + e;
}

// fragment k-slot for (lane, elem) within a 32-k block
__device__ __forceinline__ int kslot(int ln, int e) {
  return (e & 3) + 4 * (ln >> 4) + 16 * (e >> 2);
}

__device__ __forceinline__ bf16x8 pack8(float4 v0, float4 v1) {
  bf16x8 a;
  a[0] = (short)f2bf(v0.x); a[1] = (short)f2bf(v0.y);
  a[2] = (short)f2bf(v0.z); a[3] = (short)f2bf(v0.w);
  a[4] = (short)f2bf(v1.x); a[5] = (short)f2bf(v1.y);
  a[6] = (short)f2bf(v1.z); a[7] = (short)f2bf(v1.w);
  return a;
}

// ---------------------------------------------------------------------------
// k_prep: weights -> bf16 fragment layouts (t2n, n2t, W1 hi/lo, g1, g2)
// ---------------------------------------------------------------------------
__global__ __launch_bounds__(256) void k_prep(
    const float* __restrict__ t2n, const float* __restrict__ n2t,
    const float* __restrict__ W1, const float* __restrict__ g1,
    const float* __restrict__ g2,
    u16* __restrict__ t2nf, u16* __restrict__ n2tf,
    u16* __restrict__ W1h, u16* __restrict__ W1l,
    u16* __restrict__ g1f, u16* __restrict__ g2f)
{
  const int gid = blockIdx.x * 256 + threadIdx.x;
  const int stride = gridDim.x * 256;
  for (int s = gid; s < 512 * 64; s += stride) {
    const int k = s >> 6, c = s & 63;
    const int idx = bfrag_idx(k, c, 4);
    t2nf[idx] = f2bf(t2n[s]);
    const float w = W1[s];
    const u16 wh = f2bf(w);
    W1h[idx] = wh;
    W1l[idx] = f2bf(w - bf2f(wh));
  }
  for (int s = gid; s < 64 * 512; s += stride) {
    const int k = s >> 9, c = s & 511;
    n2tf[bfrag_idx(k, c, 32)] = f2bf(n2t[s]);
  }
  for (int s = gid; s < 4096; s += stride) {
    const int k = s >> 6, c = s & 63;
    g1f[bfrag_idx(k, c, 4)] = f2bf(g1[s]);
    g2f[bfrag_idx(k, c, 4)] = f2bf(g2[s]);
  }
}

// ---------------------------------------------------------------------------
// k_sp: FUSED scores + proj, one X pass, register-double-buffered A AND B
// (depth-1 software pipeline: loads for step k+1 issue before step k's MFMAs)
// ---------------------------------------------------------------------------
__global__ __launch_bounds__(256) void k_sp(
    const float* __restrict__ X, const u16* __restrict__ W1h,
    const u16* __restrict__ W1l, const u16* __restrict__ t2nf,
    const float* __restrict__ b1, const float* __restrict__ w2,
    const float* __restrict__ b2, float* __restrict__ scores,
    float* __restrict__ outStash)
{
  __shared__ __align__(16) u16 sAf[4096];  // 4 waves x 1KB wave-private
  const int tid = threadIdx.x;
  const int t0 = blockIdx.x * 64;
  const int wv = tid >> 6, ln = tid & 63;
  const int lq = ln >> 4, lr = ln & 15;
  u16* mySf = &sAf[wv * 1024];
  const float* xr = X + (size_t)(t0 + 16 * wv + lr) * D_;

  f32x4 acc[4], accP[4];
  #pragma unroll
  for (int cb = 0; cb < 4; ++cb) {
    acc[cb] = (f32x4){0.f, 0.f, 0.f, 0.f};
    accP[cb] = (f32x4){0.f, 0.f, 0.f, 0.f};
  }

  auto loadB = [&](bf16x8* Bq, int kb) {
    #pragma unroll
    for (int cb = 0; cb < 4; ++cb) {
      Bq[cb * 3 + 0] = *(const bf16x8*)&W1h[(kb * 4 + cb) * 512 + ln * 8];
      Bq[cb * 3 + 1] = *(const bf16x8*)&W1l[(kb * 4 + cb) * 512 + ln * 8];
      Bq[cb * 3 + 2] = *(const bf16x8*)&t2nf[(kb * 4 + cb) * 512 + ln * 8];
    }
  };
  auto compute = [&](const bf16x8* Bq, float4 v0, float4 v1) {
    const float xs[8] = {v0.x, v0.y, v0.z, v0.w, v1.x, v1.y, v1.z, v1.w};
    bf16x8 ah, al;
    #pragma unroll
    for (int e = 0; e < 8; ++e) {
      const u16 h = f2bf(xs[e]);
      ah[e] = (short)h;
      al[e] = (short)f2bf(xs[e] - bf2f(h));
    }
    #pragma unroll
    for (int cb = 0; cb < 4; ++cb) {
      acc[cb]  = __builtin_amdgcn_mfma_f32_16x16x32_bf16(ah, Bq[cb * 3 + 0], acc[cb], 0, 0, 0);
      acc[cb]  = __builtin_amdgcn_mfma_f32_16x16x32_bf16(ah, Bq[cb * 3 + 1], acc[cb], 0, 0, 0);
      acc[cb]  = __builtin_amdgcn_mfma_f32_16x16x32_bf16(al, Bq[cb * 3 + 0], acc[cb], 0, 0, 0);
      accP[cb] = __builtin_amdgcn_mfma_f32_16x16x32_bf16(ah, Bq[cb * 3 + 2], accP[cb], 0, 0, 0);
    }
  };

  bf16x8 Ba[12], Bb[12];
  float4 va0, va1, vb0, vb1;
  loadB(Ba, 0);
  va0 = *(const float4*)(xr + 4 * lq);
  va1 = *(const float4*)(xr + 16 + 4 * lq);
  #pragma unroll
  for (int kb = 0; kb < 16; ++kb) {
    if ((kb & 1) == 0) {
      if (kb < 15) {
        loadB(Bb, kb + 1);
        vb0 = *(const float4*)(xr + 32 * (kb + 1) + 4 * lq);
        vb1 = *(const float4*)(xr + 32 * (kb + 1) + 16 + 4 * lq);
      }
      compute(Ba, va0, va1);
    } else {
      if (kb < 15) {
        loadB(Ba, kb + 1);
        va0 = *(const float4*)(xr + 32 * (kb + 1) + 4 * lq);
        va1 = *(const float4*)(xr + 32 * (kb + 1) + 16 + 4 * lq);
      }
      compute(Bb, vb0, vb1);
    }
  }

  // ---- scores epilogue
  float b1v[4], w2v[4];
  #pragma unroll
  for (int cb = 0; cb < 4; ++cb) {
    const int col = cb * 16 + lr;
    b1v[cb] = b1[col]; w2v[cb] = w2[col];
  }
  const float b2v = b2[0];
  #pragma unroll
  for (int r = 0; r < 4; ++r) {
    float p = 0.f;
    #pragma unroll
    for (int cb = 0; cb < 4; ++cb) {
      const float h = fmaxf(acc[cb][r] + b1v[cb], 0.f);
      p = fmaf(h, w2v[cb], p);
    }
    p += __shfl_xor(p, 1); p += __shfl_xor(p, 2);
    p += __shfl_xor(p, 4); p += __shfl_xor(p, 8);
    if (lr == 0) scores[t0 + wv * 16 + 4 * lq + r] = p + b2v;
  }

  // ---- proj D->A bounce (wave-private LDS) then coalesced 16B stash
  #pragma unroll
  for (int cb = 0; cb < 4; ++cb)
    #pragma unroll
    for (int r = 0; r < 4; ++r) {
      const int idx = (cb >> 1) * 512 + (4 * lq + r + 16 * (lr >> 2)) * 8 +
                      (lr & 3) + 4 * (cb & 1);
      mySf[idx] = f2bf(accP[cb][r]);
    }
  u16* stash = (u16*)(outStash + (size_t)blockIdx.x * 32768);
  #pragma unroll
  for (int kb2 = 0; kb2 < 2; ++kb2)
    *(bf16x8*)&stash[wv * 1024 + kb2 * 512 + ln * 8] =
        *(const bf16x8*)&mySf[kb2 * 512 + ln * 8];
}

// ---------------------------------------------------------------------------
// k_select: stats + exact top-64 radix select (ballot pass-0, shfl scans)
// ---------------------------------------------------------------------------
__global__ __launch_bounds__(256) void k_select(
    const float* __restrict__ scores, int* __restrict__ top_idx,
    int* __restrict__ take_k)
{
  __shared__ float sS[N_];
  __shared__ u32 hist[256];
  __shared__ float redf[32];
  __shared__ u32 sPrefix, sRank, sCntA, sCntT;
  __shared__ int candIdx[64];
  __shared__ float candVal[64];
  __shared__ int tieIdx[128];
  const int b = blockIdx.x, tid = threadIdx.x;
  const int wv = tid >> 6, ln = tid & 63;
  const float* s = scores + (size_t)b * N_;

  float sum = 0.f, sq = 0.f;
  for (int i = tid; i < N_; i += 256) {
    const float v = s[i]; sS[i] = v; sum += v; sq = fmaf(v, v, sq);
  }
  #pragma unroll
  for (int off = 32; off > 0; off >>= 1) {
    sum += __shfl_xor(sum, off);
    sq  += __shfl_xor(sq, off);
  }
  if (ln == 0) { redf[wv] = sum; redf[8 + wv] = sq; }
  __syncthreads();
  if (tid == 0) {
    const float tot  = (redf[0] + redf[1]) + (redf[2] + redf[3]);
    const float totq = (redf[8] + redf[9]) + (redf[10] + redf[11]);
    const float mean = tot / (float)N_;
    const float var  = totq / (float)N_ - mean * mean;
    redf[16] = mean + 0.5f * sqrtf(fmaxf(var, 0.f));
  }
  __syncthreads();
  const float thr = redf[16];
  int c = 0;
  for (int i = tid; i < N_; i += 256) c += (sS[i] > thr) ? 1 : 0;
  #pragma unroll
  for (int off = 32; off > 0; off >>= 1) c += __shfl_xor(c, off);
  if (ln == 0) hist[wv] = (u32)c;
  __syncthreads();
  if (tid == 0) {
    const int cnt = (int)(hist[0] + hist[1] + hist[2] + hist[3]);
    take_k[b] = (cnt == 0) ? M_ : (cnt < M_ ? cnt : M_);
  }
  __syncthreads();

  u32 prefix = 0, rank = 64, pmask = 0;
  for (int pass = 0; pass < 4; ++pass) {
    const int shift = 24 - 8 * pass;
    hist[tid] = 0;
    __syncthreads();
    for (int i = tid; i < N_; i += 256) {
      const u32 u = __float_as_uint(sS[i]);
      const u32 key = u ^ ((u32)((int)u >> 31) | 0x80000000u);
      const bool active = (key & pmask) == prefix;
      const int bin = (int)((key >> shift) & 255u);
      if (pass == 0) {
        unsigned long long act = __ballot(active);
        while (act) {
          const int leader = (int)__builtin_ctzll(act);
          const int lbin = __shfl(bin, leader);
          const unsigned long long eq = __ballot(active && (bin == lbin));
          if (ln == leader) atomicAdd(&hist[lbin], (u32)__builtin_popcountll(eq));
          act &= ~eq;
        }
      } else {
        if (active) atomicAdd(&hist[bin], 1u);
      }
    }
    __syncthreads();
    if (tid < 64) {
      const u32 h0 = hist[4 * tid], h1 = hist[4 * tid + 1];
      const u32 h2 = hist[4 * tid + 2], h3 = hist[4 * tid + 3];
      const u32 s3 = h3, s2 = h2 + s3, s1 = h1 + s2, s0 = h0 + s1;
      u32 run = s0;
      #pragma unroll
      for (int off = 1; off < 64; off <<= 1) {
        const u32 t = (u32)__shfl_down((int)run, off);
        if (tid + off < 64) run += t;
      }
      const u32 excl = run - s0;
      const u32 c0 = s0 + excl, c1 = s1 + excl, c2 = s2 + excl, c3 = s3 + excl;
      int pick = -1; u32 nxt = 0;
      if (c0 >= rank && c1 < rank)        { pick = 0; nxt = c1; }
      else if (c1 >= rank && c2 < rank)   { pick = 1; nxt = c2; }
      else if (c2 >= rank && c3 < rank)   { pick = 2; nxt = c3; }
      else if (c3 >= rank && excl < rank) { pick = 3; nxt = excl; }
      if (pick >= 0) {
        sPrefix = prefix | ((u32)(4 * tid + pick) << shift);
        sRank = rank - nxt;
      }
    }
    __syncthreads();
    prefix = sPrefix; rank = sRank;
    pmask |= 0xFFu << shift;
    __syncthreads();
  }

  if (tid == 0) { sCntA = 0; sCntT = 0; }
  __syncthreads();
  const u32 pivot = prefix;
  for (int i = tid; i < N_; i += 256) {
    const u32 u = __float_as_uint(sS[i]);
    const u32 key = u ^ ((u32)((int)u >> 31) | 0x80000000u);
    if (key > pivot) {
      const u32 p = atomicAdd(&sCntA, 1u);
      candIdx[p] = i; candVal[p] = sS[i];
    } else if (key == pivot) {
      const u32 p = atomicAdd(&sCntT, 1u);
      if (p < 128) tieIdx[p] = i;
    }
  }
  __syncthreads();
  if (tid == 0) {
    const int nA = (int)sCntA;
    const int need = 64 - nA;
    int nT = (int)sCntT; if (nT > 128) nT = 128;
    for (int j = 0; j < need; ++j) {
      int bi = 1 << 30, bp = -1;
      for (int q = 0; q < nT; ++q) {
        const int v = tieIdx[q];
        if (v >= 0 && v < bi) { bi = v; bp = q; }
      }
      candIdx[nA + j] = bi; candVal[nA + j] = sS[bi]; tieIdx[bp] = -1;
    }
  }
  __syncthreads();
  if (tid < 64) {
    const float v = candVal[tid]; const int ii = candIdx[tid];
    int rk = 0;
    for (int j = 0; j < 64; ++j) {
      const float vj = candVal[j]; const int ij = candIdx[j];
      rk += (vj > v || (vj == v && ij < ii)) ? 1 : 0;
    }
    top_idx[b * M_ + rk] = ii;
  }
}

// ---------------------------------------------------------------------------
// fragment loaders from fp32 LDS [64][65]
// ---------------------------------------------------------------------------
__device__ __forceinline__ bf16x8 ldsA_frag(const float (*S)[65], int wv, int kb, int ln) {
  const int lr = ln & 15;
  bf16x8 a;
  #pragma unroll
  for (int e = 0; e < 8; ++e) a[e] = (short)f2bf(S[16 * wv + lr][32 * kb + kslot(ln, e)]);
  return a;
}
__device__ __forceinline__ bf16x8 ldsB_frag(const float (*S)[65], int cb, int kb, int ln) {
  const int lr = ln & 15;
  bf16x8 bb;
  #pragma unroll
  for (int e = 0; e < 8; ++e) bb[e] = (short)f2bf(S[32 * kb + kslot(ln, e)][16 * cb + lr]);
  return bb;
}
__device__ __forceinline__ bf16x8 ldsBT_frag(const float (*S)[65], int cb, int kb, int ln) {
  const int lr = ln & 15;
  bf16x8 bb;
  #pragma unroll
  for (int e = 0; e < 8; ++e) bb[e] = (short)f2bf(S[16 * cb + lr][32 * kb + kslot(ln, e)]);
  return bb;
}

// ---------------------------------------------------------------------------
// k_graph: gather + H0 + cosine adjacency + 2-layer GCN + W = Hg@n2t
// ---------------------------------------------------------------------------
__global__ __launch_bounds__(256) void k_graph(
    const float* __restrict__ X, const u16* __restrict__ t2nf,
    const u16* __restrict__ n2tf, const u16* __restrict__ g1f,
    const u16* __restrict__ g2f, const int* __restrict__ top_idx,
    const int* __restrict__ take_k, u16* __restrict__ HgTf,
    u16* __restrict__ Wf)
{
  __shared__ float sH0[64][65];
  __shared__ float sA[64][65];
  __shared__ float sT[64][65];
  __shared__ float sU[64][65];
  __shared__ float sR[64];
  const int b = blockIdx.x, tid = threadIdx.x;
  const int wv = tid >> 6, ln = tid & 63;
  const int lq = ln >> 4, lr = ln & 15;
  const int tk = take_k[b];
  const int rowm = 16 * wv + 4 * lq;

  // ---- H0 = gather(X) @ t2n (K=512), masked
  const int gidx = top_idx[b * M_ + 16 * wv + lr];
  const float* xr = X + ((size_t)b * N_ + gidx) * D_;
  f32x4 d[4];
  #pragma unroll
  for (int cb = 0; cb < 4; ++cb) d[cb] = (f32x4){0.f, 0.f, 0.f, 0.f};
  for (int kb = 0; kb < 16; ++kb) {
    const float4 v0 = *(const float4*)(xr + 32 * kb + 4 * lq);
    const float4 v1 = *(const float4*)(xr + 32 * kb + 16 + 4 * lq);
    const bf16x8 a = pack8(v0, v1);
    #pragma unroll
    for (int cb = 0; cb < 4; ++cb) {
      const bf16x8 bb = *(const bf16x8*)&t2nf[(kb * 4 + cb) * 512 + ln * 8];
      d[cb] = __builtin_amdgcn_mfma_f32_16x16x32_bf16(a, bb, d[cb], 0, 0, 0);
    }
  }
  #pragma unroll
  for (int cb = 0; cb < 4; ++cb)
    #pragma unroll
    for (int r = 0; r < 4; ++r)
      sH0[rowm + r][16 * cb + lr] = (rowm + r < tk) ? d[cb][r] : 0.f;
  __syncthreads();

  // ---- norms -> inverse
  if (tid < 64) {
    float s = 0.f;
    #pragma unroll
    for (int k = 0; k < 64; ++k) { const float v = sH0[tid][k]; s = fmaf(v, v, s); }
    sR[tid] = 1.f / fmaxf(sqrtf(s), 1e-6f);
  }
  __syncthreads();
  #pragma unroll
  for (int p = 0; p < 16; ++p) {
    const int o = tid + p * 256;
    const int i = o >> 6, k = o & 63;
    sU[i][k] = sH0[i][k] * sR[i];
  }
  __syncthreads();

  // ---- A = relu(Hn @ Hn^T), mask, +diag
  #pragma unroll
  for (int cb = 0; cb < 4; ++cb) d[cb] = (f32x4){0.f, 0.f, 0.f, 0.f};
  #pragma unroll
  for (int kb = 0; kb < 2; ++kb) {
    const bf16x8 a = ldsA_frag(sU, wv, kb, ln);
    #pragma unroll
    for (int cb = 0; cb < 4; ++cb)
      d[cb] = __builtin_amdgcn_mfma_f32_16x16x32_bf16(a, ldsBT_frag(sU, cb, kb, ln), d[cb], 0, 0, 0);
  }
  __syncthreads();
  #pragma unroll
  for (int cb = 0; cb < 4; ++cb)
    #pragma unroll
    for (int r = 0; r < 4; ++r) {
      const int row = rowm + r, col = 16 * cb + lr;
      float s = fmaxf(d[cb][r], 0.f);
      s = (row < tk && col < tk) ? s : 0.f;
      if (row == col && row < tk) s += 1.f;
      sA[row][col] = s;
    }
  __syncthreads();

  // ---- row-normalize A
  if (tid < 64) {
    float rs = 0.f;
    #pragma unroll
    for (int j = 0; j < 64; ++j) rs += sA[tid][j];
    sR[tid] = 1.f / fmaxf(rs, 1e-6f);
  }
  __syncthreads();
  #pragma unroll
  for (int p = 0; p < 16; ++p) {
    const int o = tid + p * 256;
    const int i = o >> 6, j = o & 63;
    sA[i][j] *= sR[i];
  }
  __syncthreads();

  // ---- T = A @ H0
  #pragma unroll
  for (int cb = 0; cb < 4; ++cb) d[cb] = (f32x4){0.f, 0.f, 0.f, 0.f};
  #pragma unroll
  for (int kb = 0; kb < 2; ++kb) {
    const bf16x8 a = ldsA_frag(sA, wv, kb, ln);
    #pragma unroll
    for (int cb = 0; cb < 4; ++cb)
      d[cb] = __builtin_amdgcn_mfma_f32_16x16x32_bf16(a, ldsB_frag(sH0, cb, kb, ln), d[cb], 0, 0, 0);
  }
  __syncthreads();
  #pragma unroll
  for (int cb = 0; cb < 4; ++cb)
    #pragma unroll
    for (int r = 0; r < 4; ++r) sT[rowm + r][16 * cb + lr] = d[cb][r];
  __syncthreads();

  // ---- X1 = relu(T @ g1)
  #pragma unroll
  for (int cb = 0; cb < 4; ++cb) d[cb] = (f32x4){0.f, 0.f, 0.f, 0.f};
  #pragma unroll
  for (int kb = 0; kb < 2; ++kb) {
    const bf16x8 a = ldsA_frag(sT, wv, kb, ln);
    #pragma unroll
    for (int cb = 0; cb < 4; ++cb) {
      const bf16x8 bb = *(const bf16x8*)&g1f[(kb * 4 + cb) * 512 + ln * 8];
      d[cb] = __builtin_amdgcn_mfma_f32_16x16x32_bf16(a, bb, d[cb], 0, 0, 0);
    }
  }
  __syncthreads();
  #pragma unroll
  for (int cb = 0; cb < 4; ++cb)
    #pragma unroll
    for (int r = 0; r < 4; ++r) sU[rowm + r][16 * cb + lr] = fmaxf(d[cb][r], 0.f);
  __syncthreads();

  // ---- T2 = A @ X1
  #pragma unroll
  for (int cb = 0; cb < 4; ++cb) d[cb] = (f32x4){0.f, 0.f, 0.f, 0.f};
  #pragma unroll
  for (int kb = 0; kb < 2; ++kb) {
    const bf16x8 a = ldsA_frag(sA, wv, kb, ln);
    #pragma unroll
    for (int cb = 0; cb < 4; ++cb)
      d[cb] = __builtin_amdgcn_mfma_f32_16x16x32_bf16(a, ldsB_frag(sU, cb, kb, ln), d[cb], 0, 0, 0);
  }
  __syncthreads();
  #pragma unroll
  for (int cb = 0; cb < 4; ++cb)
    #pragma unroll
    for (int r = 0; r < 4; ++r) sT[rowm + r][16 * cb + lr] = d[cb][r];
  __syncthreads();

  // ---- Hg = relu(T2 @ g2) -> HgTf frags + LDS (for W matmul)
  #pragma unroll
  for (int cb = 0; cb < 4; ++cb) d[cb] = (f32x4){0.f, 0.f, 0.f, 0.f};
  #pragma unroll
  for (int kb = 0; kb < 2; ++kb) {
    const bf16x8 a = ldsA_frag(sT, wv, kb, ln);
    #pragma unroll
    for (int cb = 0; cb < 4; ++cb) {
      const bf16x8 bb = *(const bf16x8*)&g2f[(kb * 4 + cb) * 512 + ln * 8];
      d[cb] = __builtin_amdgcn_mfma_f32_16x16x32_bf16(a, bb, d[cb], 0, 0, 0);
    }
  }
  __syncthreads();
  #pragma unroll
  for (int cb = 0; cb < 4; ++cb)
    #pragma unroll
    for (int r = 0; r < 4; ++r) {
      const int node = rowm + r, feat = 16 * cb + lr;
      const float hv = fmaxf(d[cb][r], 0.f);
      HgTf[(size_t)b * 4096 + bfrag_idx(feat, node, 4)] = f2bf(hv);
      sU[node][feat] = hv;
    }
  __syncthreads();

  // ---- W = Hg @ n2t  [m=64][d=512] -> Wf B-frags (kd = m)
  for (int chk = 0; chk < 4; ++chk) {
    f32x4 aw[8];
    #pragma unroll
    for (int c8 = 0; c8 < 8; ++c8) aw[c8] = (f32x4){0.f, 0.f, 0.f, 0.f};
    #pragma unroll
    for (int kbf = 0; kbf < 2; ++kbf) {
      const bf16x8 a = ldsA_frag(sU, wv, kbf, ln);
      #pragma unroll
      for (int c8 = 0; c8 < 8; ++c8) {
        const bf16x8 bb = *(const bf16x8*)&n2tf[(kbf * 32 + chk * 8 + c8) * 512 + ln * 8];
        aw[c8] = __builtin_amdgcn_mfma_f32_16x16x32_bf16(a, bb, aw[c8], 0, 0, 0);
      }
    }
    #pragma unroll
    for (int c8 = 0; c8 < 8; ++c8)
      #pragma unroll
      for (int r = 0; r < 4; ++r) {
        const int m = 16 * wv + 4 * lq + r;
        const int c = (chk * 8 + c8) * 16 + lr;
        Wf[(size_t)b * 32768 + bfrag_idx(m, c, 32)] = f2bf(aw[c8][r]);
      }
  }
}

// ---------------------------------------------------------------------------
// k_attn: logits(stash)->softmax->back(attn@W)+residual, float4 epilogue
// via wave-private LDS transpose; X residual loads issued before MFMAs.
// ---------------------------------------------------------------------------
__global__ __launch_bounds__(256) void k_attn(
    const float* __restrict__ X, const u16* __restrict__ HgTf,
    const u16* __restrict__ Wf, float* __restrict__ out)
{
  __shared__ __align__(16) u16 sAf[4096];           // 4 waves x 1KB wave-private
  __shared__ __align__(16) float sBo[4][16][68];    // per-wave bounce [16 rows][64+4 cols]
  const int tid = threadIdx.x;
  const int b = blockIdx.x >> 7;
  const int t0 = (blockIdx.x & 127) << 6;
  const float* Xb = X + (size_t)b * N_ * D_;
  float* Ob = out + (size_t)b * N_ * D_;
  const int wv = tid >> 6, ln = tid & 63;
  const int lq = ln >> 4, lr = ln & 15;
  u16* mySf = &sAf[wv * 1024];
  const u16* stash = (const u16*)(out + (size_t)blockIdx.x * 32768);

  // ---- P2: logits = proj @ Hg^T (K=64); proj A-frags read from stash
  f32x4 accL[4];
  #pragma unroll
  for (int cb = 0; cb < 4; ++cb) accL[cb] = (f32x4){0.f, 0.f, 0.f, 0.f};
  #pragma unroll
  for (int kb = 0; kb < 2; ++kb) {
    const bf16x8 a = *(const bf16x8*)&stash[wv * 1024 + kb * 512 + ln * 8];
    #pragma unroll
    for (int cb = 0; cb < 4; ++cb) {
      const bf16x8 bb = *(const bf16x8*)&HgTf[(size_t)b * 4096 + (kb * 4 + cb) * 512 + ln * 8];
      accL[cb] = __builtin_amdgcn_mfma_f32_16x16x32_bf16(a, bb, accL[cb], 0, 0, 0);
    }
  }
  // all stash reads complete before any wave's P7 stores can touch those rows
  __syncthreads();

  // ---- P3: softmax over m in registers
  float attnv[4][4];
  #pragma unroll
  for (int r = 0; r < 4; ++r) {
    const float v0 = accL[0][r], v1 = accL[1][r], v2 = accL[2][r], v3 = accL[3][r];
    float mx = fmaxf(fmaxf(v0, v1), fmaxf(v2, v3));
    mx = fmaxf(mx, __shfl_xor(mx, 1)); mx = fmaxf(mx, __shfl_xor(mx, 2));
    mx = fmaxf(mx, __shfl_xor(mx, 4)); mx = fmaxf(mx, __shfl_xor(mx, 8));
    const float e0 = __expf((v0 - mx) * 0.125f), e1 = __expf((v1 - mx) * 0.125f);
    const float e2 = __expf((v2 - mx) * 0.125f), e3 = __expf((v3 - mx) * 0.125f);
    float sm = (e0 + e1) + (e2 + e3);
    sm += __shfl_xor(sm, 1); sm += __shfl_xor(sm, 2);
    sm += __shfl_xor(sm, 4); sm += __shfl_xor(sm, 8);
    const float inv = 1.f / sm;
    attnv[0][r] = e0 * inv; attnv[1][r] = e1 * inv;
    attnv[2][r] = e2 * inv; attnv[3][r] = e3 * inv;
  }
  // attn D->A bounce, wave-private
  #pragma unroll
  for (int cb = 0; cb < 4; ++cb)
    #pragma unroll
    for (int r = 0; r < 4; ++r) {
      const int idx = (cb >> 1) * 512 + (4 * lq + r + 16 * (lr >> 2)) * 8 +
                      (lr & 3) + 4 * (cb & 1);
      mySf[idx] = f2bf(attnv[cb][r]);
    }

  // ---- P7: back = attn @ W (K=64) + residual, vectorized epilogue
  for (int chk = 0; chk < 4; ++chk) {
    // issue residual X loads early (independent of MFMAs below)
    float4 xres[8];
    #pragma unroll
    for (int h = 0; h < 2; ++h)
      #pragma unroll
      for (int j = 0; j < 4; ++j)
        xres[h * 4 + j] = *(const float4*)(
            Xb + (size_t)(t0 + 16 * wv + 4 * j + lq) * D_ + chk * 128 + h * 64 + 4 * lr);

    f32x4 accB[8];
    #pragma unroll
    for (int c8 = 0; c8 < 8; ++c8) accB[c8] = (f32x4){0.f, 0.f, 0.f, 0.f};
    #pragma unroll
    for (int kb = 0; kb < 2; ++kb) {
      const bf16x8 a = *(const bf16x8*)&mySf[kb * 512 + ln * 8];
      #pragma unroll
      for (int c8 = 0; c8 < 8; ++c8) {
        const bf16x8 bb = *(const bf16x8*)&Wf[(size_t)b * 32768 + (kb * 32 + chk * 8 + c8) * 512 + ln * 8];
        accB[c8] = __builtin_amdgcn_mfma_f32_16x16x32_bf16(a, bb, accB[c8], 0, 0, 0);
      }
    }
    #pragma unroll
    for (int h = 0; h < 2; ++h) {
      // scatter D-fragments into wave-private bounce tile
      #pragma unroll
      for (int c4 = 0; c4 < 4; ++c4)
        #pragma unroll
        for (int r = 0; r < 4; ++r)
          sBo[wv][4 * lq + r][c4 * 16 + lr] = accB[4 * h + c4][r];
      // read back as float4 rows + residual add + coalesced store
      #pragma unroll
      for (int j = 0; j < 4; ++j) {
        const int rloc = 4 * j + lq;
        float4 v = *(const float4*)&sBo[wv][rloc][4 * lr];
        const float4 xv = xres[h * 4 + j];
        v.x += xv.x; v.y += xv.y; v.z += xv.z; v.w += xv.w;
        *(float4*)(Ob + (size_t)(t0 + 16 * wv + rloc) * D_ + chk * 128 + h * 64 + 4 * lr) = v;
      }
    }
  }
}

// ---------------------------------------------------------------------------
extern "C" void kernel_launch(void* const* d_in, const int* in_sizes, int n_in,
                              void* d_out, int out_size, void* d_ws, size_t ws_size,
                              hipStream_t stream)
{
  (void)in_sizes; (void)n_in; (void)out_size; (void)ws_size;
  const float* X   = (const float*)d_in[0];
  const float* W1  = (const float*)d_in[1];
  const float* b1  = (const float*)d_in[2];
  const float* w2  = (const float*)d_in[3];
  const float* b2  = (const float*)d_in[4];
  const float* t2n = (const float*)d_in[5];
  const float* n2t = (const float*)d_in[6];
  const float* g1  = (const float*)d_in[7];
  const float* g2  = (const float*)d_in[8];
  float* out = (float*)d_out;

  char* ws = (char*)d_ws;
  float* scores = (float*)(ws);                  // 256 KB
  u16* t2nf     = (u16*)(ws + 262144);           // 64 KB
  u16* n2tf     = (u16*)(ws + 327680);           // 64 KB
  u16* W1h      = (u16*)(ws + 393216);           // 64 KB
  u16* W1l      = (u16*)(ws + 458752);           // 64 KB
  u16* HgTf     = (u16*)(ws + 524288);           // 64 KB
  u16* g1f      = (u16*)(ws + 589824);           // 8 KB
  u16* g2f      = (u16*)(ws + 598016);           // 8 KB
  int* top_idx  = (int*)(ws + 606208);           // 2 KB
  int* take_k   = (int*)(ws + 608256);           // 32 B
  u16* Wf       = (u16*)(ws + 609280);           // 512 KB

  k_prep<<<64, 256, 0, stream>>>(t2n, n2t, W1, g1, g2, t2nf, n2tf, W1h, W1l, g1f, g2f);
  k_sp<<<1024, 256, 0, stream>>>(X, W1h, W1l, t2nf, b1, w2, b2, scores, out);
  k_select<<<B_, 256, 0, stream>>>(scores, top_idx, take_k);
  k_graph<<<B_, 256, 0, stream>>>(X, t2nf, n2tf, g1f, g2f, top_idx, take_k, HgTf, Wf);
  k_attn<<<1024, 256, 0, stream>>>(X, HgTf, Wf, out);
}

// Round 8
// 145.928 us; speedup vs baseline: 1.2051x; 1.2051x over previous
//
#include <hip/hip_runtime.h>
#include <hip/hip_bf16.h>

#define B_ 8
#define N_ 8192
#define D_ 512
#define M_ 64

typedef unsigned short u16;
typedef unsigned int u32;
typedef __attribute__((ext_vector_type(8))) short bf16x8;
typedef __attribute__((ext_vector_type(4))) float f32x4;

__device__ __forceinline__ u16 f2bf(float f) {
  u32 u = __float_as_uint(f);
  u += 0x7FFFu + ((u >> 16) & 1u);
  return (u16)(u >> 16);
}
__device__ __forceinline__ float bf2f(u16 h) {
  return __uint_as_float(((u32)h) << 16);
}

// B-fragment index for matrix Mx[kd][c] with N cols: slot mapping shared by A.
__device__ __forceinline__ int bfrag_idx(int kd, int c, int ncols16) {
  int sub = (kd >> 5) * ncols16 + (c >> 4);
  int lane = (c & 15) + 16 * ((kd & 15) >> 2);
  int e = (kd & 3) + 4 * ((kd >> 4) & 1);
  return sub * 512 + lane * 8 + e;
}

// fragment k-slot for (lane, elem) within a 32-k block
__device__ __forceinline__ int kslot(int ln, int e) {
  return (e & 3) + 4 * (ln >> 4) + 16 * (e >> 2);
}

__device__ __forceinline__ bf16x8 pack8(float4 v0, float4 v1) {
  bf16x8 a;
  a[0] = (short)f2bf(v0.x); a[1] = (short)f2bf(v0.y);
  a[2] = (short)f2bf(v0.z); a[3] = (short)f2bf(v0.w);
  a[4] = (short)f2bf(v1.x); a[5] = (short)f2bf(v1.y);
  a[6] = (short)f2bf(v1.z); a[7] = (short)f2bf(v1.w);
  return a;
}

// ---------------------------------------------------------------------------
// k_prep: weights -> bf16 fragment layouts (t2n, n2t, W1 hi/lo, g1, g2)
// ---------------------------------------------------------------------------
__global__ __launch_bounds__(256) void k_prep(
    const float* __restrict__ t2n, const float* __restrict__ n2t,
    const float* __restrict__ W1, const float* __restrict__ g1,
    const float* __restrict__ g2,
    u16* __restrict__ t2nf, u16* __restrict__ n2tf,
    u16* __restrict__ W1h, u16* __restrict__ W1l,
    u16* __restrict__ g1f, u16* __restrict__ g2f)
{
  const int gid = blockIdx.x * 256 + threadIdx.x;
  const int stride = gridDim.x * 256;
  for (int s = gid; s < 512 * 64; s += stride) {
    const int k = s >> 6, c = s & 63;
    const int idx = bfrag_idx(k, c, 4);
    t2nf[idx] = f2bf(t2n[s]);
    const float w = W1[s];
    const u16 wh = f2bf(w);
    W1h[idx] = wh;
    W1l[idx] = f2bf(w - bf2f(wh));
  }
  for (int s = gid; s < 64 * 512; s += stride) {
    const int k = s >> 9, c = s & 511;
    n2tf[bfrag_idx(k, c, 32)] = f2bf(n2t[s]);
  }
  for (int s = gid; s < 4096; s += stride) {
    const int k = s >> 6, c = s & 63;
    g1f[bfrag_idx(k, c, 4)] = f2bf(g1[s]);
    g2f[bfrag_idx(k, c, 4)] = f2bf(g2[s]);
  }
}

// ---------------------------------------------------------------------------
// k_sp: FUSED scores + proj, one X pass, depth-3 A-prefetch ring
// (lead ~3 K-steps of MFMA issue >= HBM latency). B loads inline (L2-hot).
// ---------------------------------------------------------------------------
__global__ __launch_bounds__(256, 3) void k_sp(
    const float* __restrict__ X, const u16* __restrict__ W1h,
    const u16* __restrict__ W1l, const u16* __restrict__ t2nf,
    const float* __restrict__ b1, const float* __restrict__ w2,
    const float* __restrict__ b2, float* __restrict__ scores,
    float* __restrict__ outStash)
{
  __shared__ __align__(16) u16 sAf[4096];  // 4 waves x 1KB wave-private
  const int tid = threadIdx.x;
  const int t0 = blockIdx.x * 64;
  const int wv = tid >> 6, ln = tid & 63;
  const int lq = ln >> 4, lr = ln & 15;
  u16* mySf = &sAf[wv * 1024];
  const float* xr = X + (size_t)(t0 + 16 * wv + lr) * D_;

  f32x4 acc[4], accP[4];
  #pragma unroll
  for (int cb = 0; cb < 4; ++cb) {
    acc[cb] = (f32x4){0.f, 0.f, 0.f, 0.f};
    accP[cb] = (f32x4){0.f, 0.f, 0.f, 0.f};
  }

  float4 p0[3], p1[3];
  #pragma unroll
  for (int q = 0; q < 3; ++q) {
    p0[q] = *(const float4*)(xr + 32 * q + 4 * lq);
    p1[q] = *(const float4*)(xr + 32 * q + 16 + 4 * lq);
  }

  #pragma unroll
  for (int kb = 0; kb < 16; ++kb) {
    const int slot = kb % 3;
    const float4 v0 = p0[slot], v1 = p1[slot];
    if (kb + 3 < 16) {  // prefetch 3 steps ahead into the slot just freed
      p0[slot] = *(const float4*)(xr + 32 * (kb + 3) + 4 * lq);
      p1[slot] = *(const float4*)(xr + 32 * (kb + 3) + 16 + 4 * lq);
    }
    const float xs[8] = {v0.x, v0.y, v0.z, v0.w, v1.x, v1.y, v1.z, v1.w};
    bf16x8 ah, al;
    #pragma unroll
    for (int e = 0; e < 8; ++e) {
      const u16 h = f2bf(xs[e]);
      ah[e] = (short)h;
      al[e] = (short)f2bf(xs[e] - bf2f(h));
    }
    #pragma unroll
    for (int cb = 0; cb < 4; ++cb) {
      const bf16x8 bh = *(const bf16x8*)&W1h[(kb * 4 + cb) * 512 + ln * 8];
      const bf16x8 bl = *(const bf16x8*)&W1l[(kb * 4 + cb) * 512 + ln * 8];
      const bf16x8 bt = *(const bf16x8*)&t2nf[(kb * 4 + cb) * 512 + ln * 8];
      acc[cb]  = __builtin_amdgcn_mfma_f32_16x16x32_bf16(ah, bh, acc[cb], 0, 0, 0);
      acc[cb]  = __builtin_amdgcn_mfma_f32_16x16x32_bf16(ah, bl, acc[cb], 0, 0, 0);
      acc[cb]  = __builtin_amdgcn_mfma_f32_16x16x32_bf16(al, bh, acc[cb], 0, 0, 0);
      accP[cb] = __builtin_amdgcn_mfma_f32_16x16x32_bf16(ah, bt, accP[cb], 0, 0, 0);
    }
  }

  // ---- scores epilogue
  float b1v[4], w2v[4];
  #pragma unroll
  for (int cb = 0; cb < 4; ++cb) {
    const int col = cb * 16 + lr;
    b1v[cb] = b1[col]; w2v[cb] = w2[col];
  }
  const float b2v = b2[0];
  #pragma unroll
  for (int r = 0; r < 4; ++r) {
    float p = 0.f;
    #pragma unroll
    for (int cb = 0; cb < 4; ++cb) {
      const float h = fmaxf(acc[cb][r] + b1v[cb], 0.f);
      p = fmaf(h, w2v[cb], p);
    }
    p += __shfl_xor(p, 1); p += __shfl_xor(p, 2);
    p += __shfl_xor(p, 4); p += __shfl_xor(p, 8);
    if (lr == 0) scores[t0 + wv * 16 + 4 * lq + r] = p + b2v;
  }

  // ---- proj D->A bounce (wave-private LDS) then coalesced 16B stash
  #pragma unroll
  for (int cb = 0; cb < 4; ++cb)
    #pragma unroll
    for (int r = 0; r < 4; ++r) {
      const int idx = (cb >> 1) * 512 + (4 * lq + r + 16 * (lr >> 2)) * 8 +
                      (lr & 3) + 4 * (cb & 1);
      mySf[idx] = f2bf(accP[cb][r]);
    }
  u16* stash = (u16*)(outStash + (size_t)blockIdx.x * 32768);
  #pragma unroll
  for (int kb2 = 0; kb2 < 2; ++kb2)
    *(bf16x8*)&stash[wv * 1024 + kb2 * 512 + ln * 8] =
        *(const bf16x8*)&mySf[kb2 * 512 + ln * 8];
}

// ---------------------------------------------------------------------------
// k_select: 1024 threads (16 waves). stats + exact top-64 radix select
// (ballot pass-0, shfl scans). 4x the scan parallelism of the 256-thr version.
// ---------------------------------------------------------------------------
__global__ __launch_bounds__(1024) void k_select(
    const float* __restrict__ scores, int* __restrict__ top_idx,
    int* __restrict__ take_k)
{
  __shared__ float sS[N_];
  __shared__ u32 hist[256];
  __shared__ float redf[34];
  __shared__ u32 redu[16];
  __shared__ u32 sPrefix, sRank, sCntA, sCntT;
  __shared__ int candIdx[64];
  __shared__ float candVal[64];
  __shared__ int tieIdx[128];
  const int b = blockIdx.x, tid = threadIdx.x;
  const int wv = tid >> 6, ln = tid & 63;
  const float* s = scores + (size_t)b * N_;

  float sum = 0.f, sq = 0.f;
  for (int i = tid; i < N_; i += 1024) {
    const float v = s[i]; sS[i] = v; sum += v; sq = fmaf(v, v, sq);
  }
  #pragma unroll
  for (int off = 32; off > 0; off >>= 1) {
    sum += __shfl_xor(sum, off);
    sq  += __shfl_xor(sq, off);
  }
  if (ln == 0) { redf[wv] = sum; redf[16 + wv] = sq; }
  __syncthreads();
  if (tid == 0) {
    float tot = 0.f, totq = 0.f;
    #pragma unroll
    for (int w = 0; w < 16; ++w) { tot += redf[w]; totq += redf[16 + w]; }
    const float mean = tot / (float)N_;
    const float var  = totq / (float)N_ - mean * mean;
    redf[32] = mean + 0.5f * sqrtf(fmaxf(var, 0.f));
  }
  __syncthreads();
  const float thr = redf[32];
  int c = 0;
  for (int i = tid; i < N_; i += 1024) c += (sS[i] > thr) ? 1 : 0;
  #pragma unroll
  for (int off = 32; off > 0; off >>= 1) c += __shfl_xor(c, off);
  if (ln == 0) redu[wv] = (u32)c;
  __syncthreads();
  if (tid == 0) {
    int cnt = 0;
    #pragma unroll
    for (int w = 0; w < 16; ++w) cnt += (int)redu[w];
    take_k[b] = (cnt == 0) ? M_ : (cnt < M_ ? cnt : M_);
  }
  __syncthreads();

  u32 prefix = 0, rank = 64, pmask = 0;
  for (int pass = 0; pass < 4; ++pass) {
    const int shift = 24 - 8 * pass;
    if (tid < 256) hist[tid] = 0;
    __syncthreads();
    for (int i = tid; i < N_; i += 1024) {
      const u32 u = __float_as_uint(sS[i]);
      const u32 key = u ^ ((u32)((int)u >> 31) | 0x80000000u);
      const bool active = (key & pmask) == prefix;
      const int bin = (int)((key >> shift) & 255u);
      if (pass == 0) {
        unsigned long long act = __ballot(active);
        while (act) {
          const int leader = (int)__builtin_ctzll(act);
          const int lbin = __shfl(bin, leader);
          const unsigned long long eq = __ballot(active && (bin == lbin));
          if (ln == leader) atomicAdd(&hist[lbin], (u32)__builtin_popcountll(eq));
          act &= ~eq;
        }
      } else {
        if (active) atomicAdd(&hist[bin], 1u);
      }
    }
    __syncthreads();
    if (tid < 64) {
      const u32 h0 = hist[4 * tid], h1 = hist[4 * tid + 1];
      const u32 h2 = hist[4 * tid + 2], h3 = hist[4 * tid + 3];
      const u32 s3 = h3, s2 = h2 + s3, s1 = h1 + s2, s0 = h0 + s1;
      u32 run = s0;
      #pragma unroll
      for (int off = 1; off < 64; off <<= 1) {
        const u32 t = (u32)__shfl_down((int)run, off);
        if (tid + off < 64) run += t;
      }
      const u32 excl = run - s0;
      const u32 c0 = s0 + excl, c1 = s1 + excl, c2 = s2 + excl, c3 = s3 + excl;
      int pick = -1; u32 nxt = 0;
      if (c0 >= rank && c1 < rank)        { pick = 0; nxt = c1; }
      else if (c1 >= rank && c2 < rank)   { pick = 1; nxt = c2; }
      else if (c2 >= rank && c3 < rank)   { pick = 2; nxt = c3; }
      else if (c3 >= rank && excl < rank) { pick = 3; nxt = excl; }
      if (pick >= 0) {
        sPrefix = prefix | ((u32)(4 * tid + pick) << shift);
        sRank = rank - nxt;
      }
    }
    __syncthreads();
    prefix = sPrefix; rank = sRank;
    pmask |= 0xFFu << shift;
    __syncthreads();
  }

  if (tid == 0) { sCntA = 0; sCntT = 0; }
  __syncthreads();
  const u32 pivot = prefix;
  for (int i = tid; i < N_; i += 1024) {
    const u32 u = __float_as_uint(sS[i]);
    const u32 key = u ^ ((u32)((int)u >> 31) | 0x80000000u);
    if (key > pivot) {
      const u32 p = atomicAdd(&sCntA, 1u);
      candIdx[p] = i; candVal[p] = sS[i];
    } else if (key == pivot) {
      const u32 p = atomicAdd(&sCntT, 1u);
      if (p < 128) tieIdx[p] = i;
    }
  }
  __syncthreads();
  if (tid == 0) {
    const int nA = (int)sCntA;
    const int need = 64 - nA;
    int nT = (int)sCntT; if (nT > 128) nT = 128;
    for (int j = 0; j < need; ++j) {
      int bi = 1 << 30, bp = -1;
      for (int q = 0; q < nT; ++q) {
        const int v = tieIdx[q];
        if (v >= 0 && v < bi) { bi = v; bp = q; }
      }
      candIdx[nA + j] = bi; candVal[nA + j] = sS[bi]; tieIdx[bp] = -1;
    }
  }
  __syncthreads();
  if (tid < 64) {
    const float v = candVal[tid]; const int ii = candIdx[tid];
    int rk = 0;
    for (int j = 0; j < 64; ++j) {
      const float vj = candVal[j]; const int ij = candIdx[j];
      rk += (vj > v || (vj == v && ij < ii)) ? 1 : 0;
    }
    top_idx[b * M_ + rk] = ii;
  }
}

// ---------------------------------------------------------------------------
// fragment loaders from fp32 LDS [64][65]
// ---------------------------------------------------------------------------
__device__ __forceinline__ bf16x8 ldsA_frag(const float (*S)[65], int wv, int kb, int ln) {
  const int lr = ln & 15;
  bf16x8 a;
  #pragma unroll
  for (int e = 0; e < 8; ++e) a[e] = (short)f2bf(S[16 * wv + lr][32 * kb + kslot(ln, e)]);
  return a;
}
__device__ __forceinline__ bf16x8 ldsB_frag(const float (*S)[65], int cb, int kb, int ln) {
  const int lr = ln & 15;
  bf16x8 bb;
  #pragma unroll
  for (int e = 0; e < 8; ++e) bb[e] = (short)f2bf(S[32 * kb + kslot(ln, e)][16 * cb + lr]);
  return bb;
}
__device__ __forceinline__ bf16x8 ldsBT_frag(const float (*S)[65], int cb, int kb, int ln) {
  const int lr = ln & 15;
  bf16x8 bb;
  #pragma unroll
  for (int e = 0; e < 8; ++e) bb[e] = (short)f2bf(S[16 * cb + lr][32 * kb + kslot(ln, e)]);
  return bb;
}

// ---------------------------------------------------------------------------
// k_graph: gather + H0 + cosine adjacency + 2-layer GCN + W = Hg@n2t
// ---------------------------------------------------------------------------
__global__ __launch_bounds__(256) void k_graph(
    const float* __restrict__ X, const u16* __restrict__ t2nf,
    const u16* __restrict__ n2tf, const u16* __restrict__ g1f,
    const u16* __restrict__ g2f, const int* __restrict__ top_idx,
    const int* __restrict__ take_k, u16* __restrict__ HgTf,
    u16* __restrict__ Wf)
{
  __shared__ float sH0[64][65];
  __shared__ float sA[64][65];
  __shared__ float sT[64][65];
  __shared__ float sU[64][65];
  __shared__ float sR[64];
  const int b = blockIdx.x, tid = threadIdx.x;
  const int wv = tid >> 6, ln = tid & 63;
  const int lq = ln >> 4, lr = ln & 15;
  const int tk = take_k[b];
  const int rowm = 16 * wv + 4 * lq;

  // ---- H0 = gather(X) @ t2n (K=512), masked; depth-3 prefetch ring
  const int gidx = top_idx[b * M_ + 16 * wv + lr];
  const float* xr = X + ((size_t)b * N_ + gidx) * D_;
  f32x4 d[4];
  #pragma unroll
  for (int cb = 0; cb < 4; ++cb) d[cb] = (f32x4){0.f, 0.f, 0.f, 0.f};
  {
    float4 p0[3], p1[3];
    #pragma unroll
    for (int q = 0; q < 3; ++q) {
      p0[q] = *(const float4*)(xr + 32 * q + 4 * lq);
      p1[q] = *(const float4*)(xr + 32 * q + 16 + 4 * lq);
    }
    #pragma unroll
    for (int kb = 0; kb < 16; ++kb) {
      const int slot = kb % 3;
      const float4 v0 = p0[slot], v1 = p1[slot];
      if (kb + 3 < 16) {
        p0[slot] = *(const float4*)(xr + 32 * (kb + 3) + 4 * lq);
        p1[slot] = *(const float4*)(xr + 32 * (kb + 3) + 16 + 4 * lq);
      }
      const bf16x8 a = pack8(v0, v1);
      #pragma unroll
      for (int cb = 0; cb < 4; ++cb) {
        const bf16x8 bb = *(const bf16x8*)&t2nf[(kb * 4 + cb) * 512 + ln * 8];
        d[cb] = __builtin_amdgcn_mfma_f32_16x16x32_bf16(a, bb, d[cb], 0, 0, 0);
      }
    }
  }
  #pragma unroll
  for (int cb = 0; cb < 4; ++cb)
    #pragma unroll
    for (int r = 0; r < 4; ++r)
      sH0[rowm + r][16 * cb + lr] = (rowm + r < tk) ? d[cb][r] : 0.f;
  __syncthreads();

  // ---- norms -> inverse
  if (tid < 64) {
    float s = 0.f;
    #pragma unroll
    for (int k = 0; k < 64; ++k) { const float v = sH0[tid][k]; s = fmaf(v, v, s); }
    sR[tid] = 1.f / fmaxf(sqrtf(s), 1e-6f);
  }
  __syncthreads();
  #pragma unroll
  for (int p = 0; p < 16; ++p) {
    const int o = tid + p * 256;
    const int i = o >> 6, k = o & 63;
    sU[i][k] = sH0[i][k] * sR[i];
  }
  __syncthreads();

  // ---- A = relu(Hn @ Hn^T), mask, +diag
  #pragma unroll
  for (int cb = 0; cb < 4; ++cb) d[cb] = (f32x4){0.f, 0.f, 0.f, 0.f};
  #pragma unroll
  for (int kb = 0; kb < 2; ++kb) {
    const bf16x8 a = ldsA_frag(sU, wv, kb, ln);
    #pragma unroll
    for (int cb = 0; cb < 4; ++cb)
      d[cb] = __builtin_amdgcn_mfma_f32_16x16x32_bf16(a, ldsBT_frag(sU, cb, kb, ln), d[cb], 0, 0, 0);
  }
  __syncthreads();
  #pragma unroll
  for (int cb = 0; cb < 4; ++cb)
    #pragma unroll
    for (int r = 0; r < 4; ++r) {
      const int row = rowm + r, col = 16 * cb + lr;
      float s = fmaxf(d[cb][r], 0.f);
      s = (row < tk && col < tk) ? s : 0.f;
      if (row == col && row < tk) s += 1.f;
      sA[row][col] = s;
    }
  __syncthreads();

  // ---- row-normalize A
  if (tid < 64) {
    float rs = 0.f;
    #pragma unroll
    for (int j = 0; j < 64; ++j) rs += sA[tid][j];
    sR[tid] = 1.f / fmaxf(rs, 1e-6f);
  }
  __syncthreads();
  #pragma unroll
  for (int p = 0; p < 16; ++p) {
    const int o = tid + p * 256;
    const int i = o >> 6, j = o & 63;
    sA[i][j] *= sR[i];
  }
  __syncthreads();

  // ---- T = A @ H0
  #pragma unroll
  for (int cb = 0; cb < 4; ++cb) d[cb] = (f32x4){0.f, 0.f, 0.f, 0.f};
  #pragma unroll
  for (int kb = 0; kb < 2; ++kb) {
    const bf16x8 a = ldsA_frag(sA, wv, kb, ln);
    #pragma unroll
    for (int cb = 0; cb < 4; ++cb)
      d[cb] = __builtin_amdgcn_mfma_f32_16x16x32_bf16(a, ldsB_frag(sH0, cb, kb, ln), d[cb], 0, 0, 0);
  }
  __syncthreads();
  #pragma unroll
  for (int cb = 0; cb < 4; ++cb)
    #pragma unroll
    for (int r = 0; r < 4; ++r) sT[rowm + r][16 * cb + lr] = d[cb][r];
  __syncthreads();

  // ---- X1 = relu(T @ g1)
  #pragma unroll
  for (int cb = 0; cb < 4; ++cb) d[cb] = (f32x4){0.f, 0.f, 0.f, 0.f};
  #pragma unroll
  for (int kb = 0; kb < 2; ++kb) {
    const bf16x8 a = ldsA_frag(sT, wv, kb, ln);
    #pragma unroll
    for (int cb = 0; cb < 4; ++cb) {
      const bf16x8 bb = *(const bf16x8*)&g1f[(kb * 4 + cb) * 512 + ln * 8];
      d[cb] = __builtin_amdgcn_mfma_f32_16x16x32_bf16(a, bb, d[cb], 0, 0, 0);
    }
  }
  __syncthreads();
  #pragma unroll
  for (int cb = 0; cb < 4; ++cb)
    #pragma unroll
    for (int r = 0; r < 4; ++r) sU[rowm + r][16 * cb + lr] = fmaxf(d[cb][r], 0.f);
  __syncthreads();

  // ---- T2 = A @ X1
  #pragma unroll
  for (int cb = 0; cb < 4; ++cb) d[cb] = (f32x4){0.f, 0.f, 0.f, 0.f};
  #pragma unroll
  for (int kb = 0; kb < 2; ++kb) {
    const bf16x8 a = ldsA_frag(sA, wv, kb, ln);
    #pragma unroll
    for (int cb = 0; cb < 4; ++cb)
      d[cb] = __builtin_amdgcn_mfma_f32_16x16x32_bf16(a, ldsB_frag(sU, cb, kb, ln), d[cb], 0, 0, 0);
  }
  __syncthreads();
  #pragma unroll
  for (int cb = 0; cb < 4; ++cb)
    #pragma unroll
    for (int r = 0; r < 4; ++r) sT[rowm + r][16 * cb + lr] = d[cb][r];
  __syncthreads();

  // ---- Hg = relu(T2 @ g2) -> HgTf frags + LDS (for W matmul)
  #pragma unroll
  for (int cb = 0; cb < 4; ++cb) d[cb] = (f32x4){0.f, 0.f, 0.f, 0.f};
  #pragma unroll
  for (int kb = 0; kb < 2; ++kb) {
    const bf16x8 a = ldsA_frag(sT, wv, kb, ln);
    #pragma unroll
    for (int cb = 0; cb < 4; ++cb) {
      const bf16x8 bb = *(const bf16x8*)&g2f[(kb * 4 + cb) * 512 + ln * 8];
      d[cb] = __builtin_amdgcn_mfma_f32_16x16x32_bf16(a, bb, d[cb], 0, 0, 0);
    }
  }
  __syncthreads();
  #pragma unroll
  for (int cb = 0; cb < 4; ++cb)
    #pragma unroll
    for (int r = 0; r < 4; ++r) {
      const int node = rowm + r, feat = 16 * cb + lr;
      const float hv = fmaxf(d[cb][r], 0.f);
      HgTf[(size_t)b * 4096 + bfrag_idx(feat, node, 4)] = f2bf(hv);
      sU[node][feat] = hv;
    }
  __syncthreads();

  // ---- W = Hg @ n2t  [m=64][d=512] -> Wf B-frags (kd = m)
  for (int chk = 0; chk < 4; ++chk) {
    f32x4 aw[8];
    #pragma unroll
    for (int c8 = 0; c8 < 8; ++c8) aw[c8] = (f32x4){0.f, 0.f, 0.f, 0.f};
    #pragma unroll
    for (int kbf = 0; kbf < 2; ++kbf) {
      const bf16x8 a = ldsA_frag(sU, wv, kbf, ln);
      #pragma unroll
      for (int c8 = 0; c8 < 8; ++c8) {
        const bf16x8 bb = *(const bf16x8*)&n2tf[(kbf * 32 + chk * 8 + c8) * 512 + ln * 8];
        aw[c8] = __builtin_amdgcn_mfma_f32_16x16x32_bf16(a, bb, aw[c8], 0, 0, 0);
      }
    }
    #pragma unroll
    for (int c8 = 0; c8 < 8; ++c8)
      #pragma unroll
      for (int r = 0; r < 4; ++r) {
        const int m = 16 * wv + 4 * lq + r;
        const int c = (chk * 8 + c8) * 16 + lr;
        Wf[(size_t)b * 32768 + bfrag_idx(m, c, 32)] = f2bf(aw[c8][r]);
      }
  }
}

// ---------------------------------------------------------------------------
// k_attn: logits(stash)->softmax->back(attn@W)+residual, float4 epilogue
// via wave-private LDS transpose; X residual loads issued before MFMAs.
// ---------------------------------------------------------------------------
__global__ __launch_bounds__(256) void k_attn(
    const float* __restrict__ X, const u16* __restrict__ HgTf,
    const u16* __restrict__ Wf, float* __restrict__ out)
{
  __shared__ __align__(16) u16 sAf[4096];           // 4 waves x 1KB wave-private
  __shared__ __align__(16) float sBo[4][16][68];    // per-wave bounce [16 rows][64+4 cols]
  const int tid = threadIdx.x;
  const int b = blockIdx.x >> 7;
  const int t0 = (blockIdx.x & 127) << 6;
  const float* Xb = X + (size_t)b * N_ * D_;
  float* Ob = out + (size_t)b * N_ * D_;
  const int wv = tid >> 6, ln = tid & 63;
  const int lq = ln >> 4, lr = ln & 15;
  u16* mySf = &sAf[wv * 1024];
  const u16* stash = (const u16*)(out + (size_t)blockIdx.x * 32768);

  // ---- P2: logits = proj @ Hg^T (K=64); proj A-frags read from stash
  f32x4 accL[4];
  #pragma unroll
  for (int cb = 0; cb < 4; ++cb) accL[cb] = (f32x4){0.f, 0.f, 0.f, 0.f};
  #pragma unroll
  for (int kb = 0; kb < 2; ++kb) {
    const bf16x8 a = *(const bf16x8*)&stash[wv * 1024 + kb * 512 + ln * 8];
    #pragma unroll
    for (int cb = 0; cb < 4; ++cb) {
      const bf16x8 bb = *(const bf16x8*)&HgTf[(size_t)b * 4096 + (kb * 4 + cb) * 512 + ln * 8];
      accL[cb] = __builtin_amdgcn_mfma_f32_16x16x32_bf16(a, bb, accL[cb], 0, 0, 0);
    }
  }
  // all stash reads complete before any wave's P7 stores can touch those rows
  __syncthreads();

  // ---- P3: softmax over m in registers
  float attnv[4][4];
  #pragma unroll
  for (int r = 0; r < 4; ++r) {
    const float v0 = accL[0][r], v1 = accL[1][r], v2 = accL[2][r], v3 = accL[3][r];
    float mx = fmaxf(fmaxf(v0, v1), fmaxf(v2, v3));
    mx = fmaxf(mx, __shfl_xor(mx, 1)); mx = fmaxf(mx, __shfl_xor(mx, 2));
    mx = fmaxf(mx, __shfl_xor(mx, 4)); mx = fmaxf(mx, __shfl_xor(mx, 8));
    const float e0 = __expf((v0 - mx) * 0.125f), e1 = __expf((v1 - mx) * 0.125f);
    const float e2 = __expf((v2 - mx) * 0.125f), e3 = __expf((v3 - mx) * 0.125f);
    float sm = (e0 + e1) + (e2 + e3);
    sm += __shfl_xor(sm, 1); sm += __shfl_xor(sm, 2);
    sm += __shfl_xor(sm, 4); sm += __shfl_xor(sm, 8);
    const float inv = 1.f / sm;
    attnv[0][r] = e0 * inv; attnv[1][r] = e1 * inv;
    attnv[2][r] = e2 * inv; attnv[3][r] = e3 * inv;
  }
  // attn D->A bounce, wave-private
  #pragma unroll
  for (int cb = 0; cb < 4; ++cb)
    #pragma unroll
    for (int r = 0; r < 4; ++r) {
      const int idx = (cb >> 1) * 512 + (4 * lq + r + 16 * (lr >> 2)) * 8 +
                      (lr & 3) + 4 * (cb & 1);
      mySf[idx] = f2bf(attnv[cb][r]);
    }

  // ---- P7: back = attn @ W (K=64) + residual, vectorized epilogue
  for (int chk = 0; chk < 4; ++chk) {
    // issue residual X loads early (independent of MFMAs below)
    float4 xres[8];
    #pragma unroll
    for (int h = 0; h < 2; ++h)
      #pragma unroll
      for (int j = 0; j < 4; ++j)
        xres[h * 4 + j] = *(const float4*)(
            Xb + (size_t)(t0 + 16 * wv + 4 * j + lq) * D_ + chk * 128 + h * 64 + 4 * lr);

    f32x4 accB[8];
    #pragma unroll
    for (int c8 = 0; c8 < 8; ++c8) accB[c8] = (f32x4){0.f, 0.f, 0.f, 0.f};
    #pragma unroll
    for (int kb = 0; kb < 2; ++kb) {
      const bf16x8 a = *(const bf16x8*)&mySf[kb * 512 + ln * 8];
      #pragma unroll
      for (int c8 = 0; c8 < 8; ++c8) {
        const bf16x8 bb = *(const bf16x8*)&Wf[(size_t)b * 32768 + (kb * 32 + chk * 8 + c8) * 512 + ln * 8];
        accB[c8] = __builtin_amdgcn_mfma_f32_16x16x32_bf16(a, bb, accB[c8], 0, 0, 0);
      }
    }
    #pragma unroll
    for (int h = 0; h < 2; ++h) {
      #pragma unroll
      for (int c4 = 0; c4 < 4; ++c4)
        #pragma unroll
        for (int r = 0; r < 4; ++r)
          sBo[wv][4 * lq + r][c4 * 16 + lr] = accB[4 * h + c4][r];
      #pragma unroll
      for (int j = 0; j < 4; ++j) {
        const int rloc = 4 * j + lq;
        float4 v = *(const float4*)&sBo[wv][rloc][4 * lr];
        const float4 xv = xres[h * 4 + j];
        v.x += xv.x; v.y += xv.y; v.z += xv.z; v.w += xv.w;
        *(float4*)(Ob + (size_t)(t0 + 16 * wv + rloc) * D_ + chk * 128 + h * 64 + 4 * lr) = v;
      }
    }
  }
}

// ---------------------------------------------------------------------------
extern "C" void kernel_launch(void* const* d_in, const int* in_sizes, int n_in,
                              void* d_out, int out_size, void* d_ws, size_t ws_size,
                              hipStream_t stream)
{
  (void)in_sizes; (void)n_in; (void)out_size; (void)ws_size;
  const float* X   = (const float*)d_in[0];
  const float* W1  = (const float*)d_in[1];
  const float* b1  = (const float*)d_in[2];
  const float* w2  = (const float*)d_in[3];
  const float* b2  = (const float*)d_in[4];
  const float* t2n = (const float*)d_in[5];
  const float* n2t = (const float*)d_in[6];
  const float* g1  = (const float*)d_in[7];
  const float* g2  = (const float*)d_in[8];
  float* out = (float*)d_out;

  char* ws = (char*)d_ws;
  float* scores = (float*)(ws);                  // 256 KB
  u16* t2nf     = (u16*)(ws + 262144);           // 64 KB
  u16* n2tf     = (u16*)(ws + 327680);           // 64 KB
  u16* W1h      = (u16*)(ws + 393216);           // 64 KB
  u16* W1l      = (u16*)(ws + 458752);           // 64 KB
  u16* HgTf     = (u16*)(ws + 524288);           // 64 KB
  u16* g1f      = (u16*)(ws + 589824);           // 8 KB
  u16* g2f      = (u16*)(ws + 598016);           // 8 KB
  int* top_idx  = (int*)(ws + 606208);           // 2 KB
  int* take_k   = (int*)(ws + 608256);           // 32 B
  u16* Wf       = (u16*)(ws + 609280);           // 512 KB

  k_prep<<<64, 256, 0, stream>>>(t2n, n2t, W1, g1, g2, t2nf, n2tf, W1h, W1l, g1f, g2f);
  k_sp<<<1024, 256, 0, stream>>>(X, W1h, W1l, t2nf, b1, w2, b2, scores, out);
  k_select<<<B_, 1024, 0, stream>>>(scores, top_idx, take_k);
  k_graph<<<B_, 256, 0, stream>>>(X, t2nf, n2tf, g1f, g2f, top_idx, take_k, HgTf, Wf);
  k_attn<<<1024, 256, 0, stream>>>(X, HgTf, Wf, out);
}

// Round 9
// 132.267 us; speedup vs baseline: 1.3295x; 1.1033x over previous
//
#include <hip/hip_runtime.h>
#include <hip/hip_bf16.h>

#define B_ 8
#define N_ 8192
#define D_ 512
#define M_ 64

typedef unsigned short u16;
typedef unsigned int u32;
typedef __attribute__((ext_vector_type(8))) short bf16x8;
typedef __attribute__((ext_vector_type(4))) float f32x4;

__device__ __forceinline__ u16 f2bf(float f) {
  u32 u = __float_as_uint(f);
  u += 0x7FFFu + ((u >> 16) & 1u);
  return (u16)(u >> 16);
}
__device__ __forceinline__ float bf2f(u16 h) {
  return __uint_as_float(((u32)h) << 16);
}

// B-fragment index for matrix Mx[kd][c] with N cols: slot mapping shared by A.
__device__ __forceinline__ int bfrag_idx(int kd, int c, int ncols16) {
  int sub = (kd >> 5) * ncols16 + (c >> 4);
  int lane = (c & 15) + 16 * ((kd & 15) >> 2);
  int e = (kd & 3) + 4 * ((kd >> 4) & 1);
  return sub * 512 + lane * 8 + e;
}

// fragment k-slot for (lane, elem) within a 32-k block
__device__ __forceinline__ int kslot(int ln, int e) {
  return (e & 3) + 4 * (ln >> 4) + 16 * (e >> 2);
}

__device__ __forceinline__ bf16x8 pack8(float4 v0, float4 v1) {
  bf16x8 a;
  a[0] = (short)f2bf(v0.x); a[1] = (short)f2bf(v0.y);
  a[2] = (short)f2bf(v0.z); a[3] = (short)f2bf(v0.w);
  a[4] = (short)f2bf(v1.x); a[5] = (short)f2bf(v1.y);
  a[6] = (short)f2bf(v1.z); a[7] = (short)f2bf(v1.w);
  return a;
}

// ---------------------------------------------------------------------------
// k_prep: weights -> bf16 fragment layouts (t2n, n2t, W1 hi/lo, g1, g2)
// ---------------------------------------------------------------------------
__global__ __launch_bounds__(256) void k_prep(
    const float* __restrict__ t2n, const float* __restrict__ n2t,
    const float* __restrict__ W1, const float* __restrict__ g1,
    const float* __restrict__ g2,
    u16* __restrict__ t2nf, u16* __restrict__ n2tf,
    u16* __restrict__ W1h, u16* __restrict__ W1l,
    u16* __restrict__ g1f, u16* __restrict__ g2f)
{
  const int gid = blockIdx.x * 256 + threadIdx.x;
  const int stride = gridDim.x * 256;
  for (int s = gid; s < 512 * 64; s += stride) {
    const int k = s >> 6, c = s & 63;
    const int idx = bfrag_idx(k, c, 4);
    t2nf[idx] = f2bf(t2n[s]);
    const float w = W1[s];
    const u16 wh = f2bf(w);
    W1h[idx] = wh;
    W1l[idx] = f2bf(w - bf2f(wh));
  }
  for (int s = gid; s < 64 * 512; s += stride) {
    const int k = s >> 9, c = s & 511;
    n2tf[bfrag_idx(k, c, 32)] = f2bf(n2t[s]);
  }
  for (int s = gid; s < 4096; s += stride) {
    const int k = s >> 6, c = s & 63;
    g1f[bfrag_idx(k, c, 4)] = f2bf(g1[s]);
    g2f[bfrag_idx(k, c, 4)] = f2bf(g2[s]);
  }
}

// ---------------------------------------------------------------------------
// k_sp: FUSED scores + proj, one X pass.
// B operands (12 KB/K-step, identical across waves) staged in LDS once per
// block (T14: load-early to regs, ds_write after barrier) -> cuts L1 vmem 4x.
// A loads stay direct (1-step lead; TLP at 4 blocks/CU covers latency).
// ---------------------------------------------------------------------------
__global__ __launch_bounds__(256, 4) void k_sp(
    const float* __restrict__ X, const u16* __restrict__ W1h,
    const u16* __restrict__ W1l, const u16* __restrict__ t2nf,
    const float* __restrict__ b1, const float* __restrict__ w2,
    const float* __restrict__ b2, float* __restrict__ scores,
    float* __restrict__ outStash)
{
  __shared__ __align__(16) u16 sB[6144];   // 12 frags x 512 u16 = 12 KB
  __shared__ __align__(16) u16 sAf[4096];  // proj D->A bounce (post-loop)
  const int tid = threadIdx.x;
  const int t0 = blockIdx.x * 64;
  const int wv = tid >> 6, ln = tid & 63;
  const int lq = ln >> 4, lr = ln & 15;
  u16* mySf = &sAf[wv * 1024];
  const float* xr = X + (size_t)(t0 + 16 * wv + lr) * D_;

  f32x4 acc[4], accP[4];
  #pragma unroll
  for (int cb = 0; cb < 4; ++cb) {
    acc[cb] = (f32x4){0.f, 0.f, 0.f, 0.f};
    accP[cb] = (f32x4){0.f, 0.f, 0.f, 0.f};
  }

  // stage-unit mapping: wave wv stages frags {wv, wv+4, wv+8}; frag f=(cb,mat)
  auto gsrc = [&](int f, int kb) -> const u16* {
    const int cb = f / 3, mat = f % 3;
    const u16* mp = (mat == 0) ? W1h : (mat == 1) ? W1l : t2nf;
    return mp + (kb * 4 + cb) * 512 + ln * 8;
  };

  bf16x8 wr[3];
  #pragma unroll
  for (int j = 0; j < 3; ++j) wr[j] = *(const bf16x8*)gsrc(j * 4 + wv, 0);
  float4 va0 = *(const float4*)(xr + 4 * lq);
  float4 va1 = *(const float4*)(xr + 16 + 4 * lq);

  for (int kb = 0; kb < 16; ++kb) {
    __syncthreads();   // all waves done reading sB from previous step
    #pragma unroll
    for (int j = 0; j < 3; ++j)
      *(bf16x8*)&sB[(j * 4 + wv) * 512 + ln * 8] = wr[j];
    __syncthreads();   // sB populated
    const float4 v0 = va0, v1 = va1;
    if (kb < 15) {     // issue next-step loads; they complete under the MFMAs
      #pragma unroll
      for (int j = 0; j < 3; ++j) wr[j] = *(const bf16x8*)gsrc(j * 4 + wv, kb + 1);
      va0 = *(const float4*)(xr + 32 * (kb + 1) + 4 * lq);
      va1 = *(const float4*)(xr + 32 * (kb + 1) + 16 + 4 * lq);
    }
    const float xs[8] = {v0.x, v0.y, v0.z, v0.w, v1.x, v1.y, v1.z, v1.w};
    bf16x8 ah, al;
    #pragma unroll
    for (int e = 0; e < 8; ++e) {
      const u16 h = f2bf(xs[e]);
      ah[e] = (short)h;
      al[e] = (short)f2bf(xs[e] - bf2f(h));
    }
    #pragma unroll
    for (int cb = 0; cb < 4; ++cb) {
      const bf16x8 bh = *(const bf16x8*)&sB[(cb * 3 + 0) * 512 + ln * 8];
      const bf16x8 bl = *(const bf16x8*)&sB[(cb * 3 + 1) * 512 + ln * 8];
      const bf16x8 bt = *(const bf16x8*)&sB[(cb * 3 + 2) * 512 + ln * 8];
      acc[cb]  = __builtin_amdgcn_mfma_f32_16x16x32_bf16(ah, bh, acc[cb], 0, 0, 0);
      acc[cb]  = __builtin_amdgcn_mfma_f32_16x16x32_bf16(ah, bl, acc[cb], 0, 0, 0);
      acc[cb]  = __builtin_amdgcn_mfma_f32_16x16x32_bf16(al, bh, acc[cb], 0, 0, 0);
      accP[cb] = __builtin_amdgcn_mfma_f32_16x16x32_bf16(ah, bt, accP[cb], 0, 0, 0);
    }
  }

  // ---- scores epilogue
  float b1v[4], w2v[4];
  #pragma unroll
  for (int cb = 0; cb < 4; ++cb) {
    const int col = cb * 16 + lr;
    b1v[cb] = b1[col]; w2v[cb] = w2[col];
  }
  const float b2v = b2[0];
  #pragma unroll
  for (int r = 0; r < 4; ++r) {
    float p = 0.f;
    #pragma unroll
    for (int cb = 0; cb < 4; ++cb) {
      const float h = fmaxf(acc[cb][r] + b1v[cb], 0.f);
      p = fmaf(h, w2v[cb], p);
    }
    p += __shfl_xor(p, 1); p += __shfl_xor(p, 2);
    p += __shfl_xor(p, 4); p += __shfl_xor(p, 8);
    if (lr == 0) scores[t0 + wv * 16 + 4 * lq + r] = p + b2v;
  }

  // ---- proj D->A bounce (wave-private LDS) then coalesced 16B stash
  #pragma unroll
  for (int cb = 0; cb < 4; ++cb)
    #pragma unroll
    for (int r = 0; r < 4; ++r) {
      const int idx = (cb >> 1) * 512 + (4 * lq + r + 16 * (lr >> 2)) * 8 +
                      (lr & 3) + 4 * (cb & 1);
      mySf[idx] = f2bf(accP[cb][r]);
    }
  u16* stash = (u16*)(outStash + (size_t)blockIdx.x * 32768);
  #pragma unroll
  for (int kb2 = 0; kb2 < 2; ++kb2)
    *(bf16x8*)&stash[wv * 1024 + kb2 * 512 + ln * 8] =
        *(const bf16x8*)&mySf[kb2 * 512 + ln * 8];
}

// ---------------------------------------------------------------------------
// k_select: 1024 threads (16 waves). stats + exact top-64 radix select
// (ballot pass-0, shfl scans).
// ---------------------------------------------------------------------------
__global__ __launch_bounds__(1024) void k_select(
    const float* __restrict__ scores, int* __restrict__ top_idx,
    int* __restrict__ take_k)
{
  __shared__ float sS[N_];
  __shared__ u32 hist[256];
  __shared__ float redf[34];
  __shared__ u32 redu[16];
  __shared__ u32 sPrefix, sRank, sCntA, sCntT;
  __shared__ int candIdx[64];
  __shared__ float candVal[64];
  __shared__ int tieIdx[128];
  const int b = blockIdx.x, tid = threadIdx.x;
  const int wv = tid >> 6, ln = tid & 63;
  const float* s = scores + (size_t)b * N_;

  float sum = 0.f, sq = 0.f;
  for (int i = tid; i < N_; i += 1024) {
    const float v = s[i]; sS[i] = v; sum += v; sq = fmaf(v, v, sq);
  }
  #pragma unroll
  for (int off = 32; off > 0; off >>= 1) {
    sum += __shfl_xor(sum, off);
    sq  += __shfl_xor(sq, off);
  }
  if (ln == 0) { redf[wv] = sum; redf[16 + wv] = sq; }
  __syncthreads();
  if (tid == 0) {
    float tot = 0.f, totq = 0.f;
    #pragma unroll
    for (int w = 0; w < 16; ++w) { tot += redf[w]; totq += redf[16 + w]; }
    const float mean = tot / (float)N_;
    const float var  = totq / (float)N_ - mean * mean;
    redf[32] = mean + 0.5f * sqrtf(fmaxf(var, 0.f));
  }
  __syncthreads();
  const float thr = redf[32];
  int c = 0;
  for (int i = tid; i < N_; i += 1024) c += (sS[i] > thr) ? 1 : 0;
  #pragma unroll
  for (int off = 32; off > 0; off >>= 1) c += __shfl_xor(c, off);
  if (ln == 0) redu[wv] = (u32)c;
  __syncthreads();
  if (tid == 0) {
    int cnt = 0;
    #pragma unroll
    for (int w = 0; w < 16; ++w) cnt += (int)redu[w];
    take_k[b] = (cnt == 0) ? M_ : (cnt < M_ ? cnt : M_);
  }
  __syncthreads();

  u32 prefix = 0, rank = 64, pmask = 0;
  for (int pass = 0; pass < 4; ++pass) {
    const int shift = 24 - 8 * pass;
    if (tid < 256) hist[tid] = 0;
    __syncthreads();
    for (int i = tid; i < N_; i += 1024) {
      const u32 u = __float_as_uint(sS[i]);
      const u32 key = u ^ ((u32)((int)u >> 31) | 0x80000000u);
      const bool active = (key & pmask) == prefix;
      const int bin = (int)((key >> shift) & 255u);
      if (pass == 0) {
        unsigned long long act = __ballot(active);
        while (act) {
          const int leader = (int)__builtin_ctzll(act);
          const int lbin = __shfl(bin, leader);
          const unsigned long long eq = __ballot(active && (bin == lbin));
          if (ln == leader) atomicAdd(&hist[lbin], (u32)__builtin_popcountll(eq));
          act &= ~eq;
        }
      } else {
        if (active) atomicAdd(&hist[bin], 1u);
      }
    }
    __syncthreads();
    if (tid < 64) {
      const u32 h0 = hist[4 * tid], h1 = hist[4 * tid + 1];
      const u32 h2 = hist[4 * tid + 2], h3 = hist[4 * tid + 3];
      const u32 s3 = h3, s2 = h2 + s3, s1 = h1 + s2, s0 = h0 + s1;
      u32 run = s0;
      #pragma unroll
      for (int off = 1; off < 64; off <<= 1) {
        const u32 t = (u32)__shfl_down((int)run, off);
        if (tid + off < 64) run += t;
      }
      const u32 excl = run - s0;
      const u32 c0 = s0 + excl, c1 = s1 + excl, c2 = s2 + excl, c3 = s3 + excl;
      int pick = -1; u32 nxt = 0;
      if (c0 >= rank && c1 < rank)        { pick = 0; nxt = c1; }
      else if (c1 >= rank && c2 < rank)   { pick = 1; nxt = c2; }
      else if (c2 >= rank && c3 < rank)   { pick = 2; nxt = c3; }
      else if (c3 >= rank && excl < rank) { pick = 3; nxt = excl; }
      if (pick >= 0) {
        sPrefix = prefix | ((u32)(4 * tid + pick) << shift);
        sRank = rank - nxt;
      }
    }
    __syncthreads();
    prefix = sPrefix; rank = sRank;
    pmask |= 0xFFu << shift;
    __syncthreads();
  }

  if (tid == 0) { sCntA = 0; sCntT = 0; }
  __syncthreads();
  const u32 pivot = prefix;
  for (int i = tid; i < N_; i += 1024) {
    const u32 u = __float_as_uint(sS[i]);
    const u32 key = u ^ ((u32)((int)u >> 31) | 0x80000000u);
    if (key > pivot) {
      const u32 p = atomicAdd(&sCntA, 1u);
      candIdx[p] = i; candVal[p] = sS[i];
    } else if (key == pivot) {
      const u32 p = atomicAdd(&sCntT, 1u);
      if (p < 128) tieIdx[p] = i;
    }
  }
  __syncthreads();
  if (tid == 0) {
    const int nA = (int)sCntA;
    const int need = 64 - nA;
    int nT = (int)sCntT; if (nT > 128) nT = 128;
    for (int j = 0; j < need; ++j) {
      int bi = 1 << 30, bp = -1;
      for (int q = 0; q < nT; ++q) {
        const int v = tieIdx[q];
        if (v >= 0 && v < bi) { bi = v; bp = q; }
      }
      candIdx[nA + j] = bi; candVal[nA + j] = sS[bi]; tieIdx[bp] = -1;
    }
  }
  __syncthreads();
  if (tid < 64) {
    const float v = candVal[tid]; const int ii = candIdx[tid];
    int rk = 0;
    for (int j = 0; j < 64; ++j) {
      const float vj = candVal[j]; const int ij = candIdx[j];
      rk += (vj > v || (vj == v && ij < ii)) ? 1 : 0;
    }
    top_idx[b * M_ + rk] = ii;
  }
}

// ---------------------------------------------------------------------------
// fragment loaders from fp32 LDS [64][65]
// ---------------------------------------------------------------------------
__device__ __forceinline__ bf16x8 ldsA_frag(const float (*S)[65], int wv, int kb, int ln) {
  const int lr = ln & 15;
  bf16x8 a;
  #pragma unroll
  for (int e = 0; e < 8; ++e) a[e] = (short)f2bf(S[16 * wv + lr][32 * kb + kslot(ln, e)]);
  return a;
}
__device__ __forceinline__ bf16x8 ldsB_frag(const float (*S)[65], int cb, int kb, int ln) {
  const int lr = ln & 15;
  bf16x8 bb;
  #pragma unroll
  for (int e = 0; e < 8; ++e) bb[e] = (short)f2bf(S[32 * kb + kslot(ln, e)][16 * cb + lr]);
  return bb;
}
__device__ __forceinline__ bf16x8 ldsBT_frag(const float (*S)[65], int cb, int kb, int ln) {
  const int lr = ln & 15;
  bf16x8 bb;
  #pragma unroll
  for (int e = 0; e < 8; ++e) bb[e] = (short)f2bf(S[16 * cb + lr][32 * kb + kslot(ln, e)]);
  return bb;
}

// ---------------------------------------------------------------------------
// k_graph: gather + H0 + cosine adjacency + 2-layer GCN + W = Hg@n2t
// ---------------------------------------------------------------------------
__global__ __launch_bounds__(256) void k_graph(
    const float* __restrict__ X, const u16* __restrict__ t2nf,
    const u16* __restrict__ n2tf, const u16* __restrict__ g1f,
    const u16* __restrict__ g2f, const int* __restrict__ top_idx,
    const int* __restrict__ take_k, u16* __restrict__ HgTf,
    u16* __restrict__ Wf)
{
  __shared__ float sH0[64][65];
  __shared__ float sA[64][65];
  __shared__ float sT[64][65];
  __shared__ float sU[64][65];
  __shared__ float sR[64];
  const int b = blockIdx.x, tid = threadIdx.x;
  const int wv = tid >> 6, ln = tid & 63;
  const int lq = ln >> 4, lr = ln & 15;
  const int tk = take_k[b];
  const int rowm = 16 * wv + 4 * lq;

  // ---- H0 = gather(X) @ t2n (K=512), masked; depth-3 prefetch ring
  const int gidx = top_idx[b * M_ + 16 * wv + lr];
  const float* xr = X + ((size_t)b * N_ + gidx) * D_;
  f32x4 d[4];
  #pragma unroll
  for (int cb = 0; cb < 4; ++cb) d[cb] = (f32x4){0.f, 0.f, 0.f, 0.f};
  {
    float4 p0[3], p1[3];
    #pragma unroll
    for (int q = 0; q < 3; ++q) {
      p0[q] = *(const float4*)(xr + 32 * q + 4 * lq);
      p1[q] = *(const float4*)(xr + 32 * q + 16 + 4 * lq);
    }
    #pragma unroll
    for (int kb = 0; kb < 16; ++kb) {
      const int slot = kb % 3;
      const float4 v0 = p0[slot], v1 = p1[slot];
      if (kb + 3 < 16) {
        p0[slot] = *(const float4*)(xr + 32 * (kb + 3) + 4 * lq);
        p1[slot] = *(const float4*)(xr + 32 * (kb + 3) + 16 + 4 * lq);
      }
      const bf16x8 a = pack8(v0, v1);
      #pragma unroll
      for (int cb = 0; cb < 4; ++cb) {
        const bf16x8 bb = *(const bf16x8*)&t2nf[(kb * 4 + cb) * 512 + ln * 8];
        d[cb] = __builtin_amdgcn_mfma_f32_16x16x32_bf16(a, bb, d[cb], 0, 0, 0);
      }
    }
  }
  #pragma unroll
  for (int cb = 0; cb < 4; ++cb)
    #pragma unroll
    for (int r = 0; r < 4; ++r)
      sH0[rowm + r][16 * cb + lr] = (rowm + r < tk) ? d[cb][r] : 0.f;
  __syncthreads();

  // ---- norms -> inverse
  if (tid < 64) {
    float s = 0.f;
    #pragma unroll
    for (int k = 0; k < 64; ++k) { const float v = sH0[tid][k]; s = fmaf(v, v, s); }
    sR[tid] = 1.f / fmaxf(sqrtf(s), 1e-6f);
  }
  __syncthreads();
  #pragma unroll
  for (int p = 0; p < 16; ++p) {
    const int o = tid + p * 256;
    const int i = o >> 6, k = o & 63;
    sU[i][k] = sH0[i][k] * sR[i];
  }
  __syncthreads();

  // ---- A = relu(Hn @ Hn^T), mask, +diag
  #pragma unroll
  for (int cb = 0; cb < 4; ++cb) d[cb] = (f32x4){0.f, 0.f, 0.f, 0.f};
  #pragma unroll
  for (int kb = 0; kb < 2; ++kb) {
    const bf16x8 a = ldsA_frag(sU, wv, kb, ln);
    #pragma unroll
    for (int cb = 0; cb < 4; ++cb)
      d[cb] = __builtin_amdgcn_mfma_f32_16x16x32_bf16(a, ldsBT_frag(sU, cb, kb, ln), d[cb], 0, 0, 0);
  }
  __syncthreads();
  #pragma unroll
  for (int cb = 0; cb < 4; ++cb)
    #pragma unroll
    for (int r = 0; r < 4; ++r) {
      const int row = rowm + r, col = 16 * cb + lr;
      float s = fmaxf(d[cb][r], 0.f);
      s = (row < tk && col < tk) ? s : 0.f;
      if (row == col && row < tk) s += 1.f;
      sA[row][col] = s;
    }
  __syncthreads();

  // ---- row-normalize A
  if (tid < 64) {
    float rs = 0.f;
    #pragma unroll
    for (int j = 0; j < 64; ++j) rs += sA[tid][j];
    sR[tid] = 1.f / fmaxf(rs, 1e-6f);
  }
  __syncthreads();
  #pragma unroll
  for (int p = 0; p < 16; ++p) {
    const int o = tid + p * 256;
    const int i = o >> 6, j = o & 63;
    sA[i][j] *= sR[i];
  }
  __syncthreads();

  // ---- T = A @ H0
  #pragma unroll
  for (int cb = 0; cb < 4; ++cb) d[cb] = (f32x4){0.f, 0.f, 0.f, 0.f};
  #pragma unroll
  for (int kb = 0; kb < 2; ++kb) {
    const bf16x8 a = ldsA_frag(sA, wv, kb, ln);
    #pragma unroll
    for (int cb = 0; cb < 4; ++cb)
      d[cb] = __builtin_amdgcn_mfma_f32_16x16x32_bf16(a, ldsB_frag(sH0, cb, kb, ln), d[cb], 0, 0, 0);
  }
  __syncthreads();
  #pragma unroll
  for (int cb = 0; cb < 4; ++cb)
    #pragma unroll
    for (int r = 0; r < 4; ++r) sT[rowm + r][16 * cb + lr] = d[cb][r];
  __syncthreads();

  // ---- X1 = relu(T @ g1)
  #pragma unroll
  for (int cb = 0; cb < 4; ++cb) d[cb] = (f32x4){0.f, 0.f, 0.f, 0.f};
  #pragma unroll
  for (int kb = 0; kb < 2; ++kb) {
    const bf16x8 a = ldsA_frag(sT, wv, kb, ln);
    #pragma unroll
    for (int cb = 0; cb < 4; ++cb) {
      const bf16x8 bb = *(const bf16x8*)&g1f[(kb * 4 + cb) * 512 + ln * 8];
      d[cb] = __builtin_amdgcn_mfma_f32_16x16x32_bf16(a, bb, d[cb], 0, 0, 0);
    }
  }
  __syncthreads();
  #pragma unroll
  for (int cb = 0; cb < 4; ++cb)
    #pragma unroll
    for (int r = 0; r < 4; ++r) sU[rowm + r][16 * cb + lr] = fmaxf(d[cb][r], 0.f);
  __syncthreads();

  // ---- T2 = A @ X1
  #pragma unroll
  for (int cb = 0; cb < 4; ++cb) d[cb] = (f32x4){0.f, 0.f, 0.f, 0.f};
  #pragma unroll
  for (int kb = 0; kb < 2; ++kb) {
    const bf16x8 a = ldsA_frag(sA, wv, kb, ln);
    #pragma unroll
    for (int cb = 0; cb < 4; ++cb)
      d[cb] = __builtin_amdgcn_mfma_f32_16x16x32_bf16(a, ldsB_frag(sU, cb, kb, ln), d[cb], 0, 0, 0);
  }
  __syncthreads();
  #pragma unroll
  for (int cb = 0; cb < 4; ++cb)
    #pragma unroll
    for (int r = 0; r < 4; ++r) sT[rowm + r][16 * cb + lr] = d[cb][r];
  __syncthreads();

  // ---- Hg = relu(T2 @ g2) -> HgTf frags + LDS (for W matmul)
  #pragma unroll
  for (int cb = 0; cb < 4; ++cb) d[cb] = (f32x4){0.f, 0.f, 0.f, 0.f};
  #pragma unroll
  for (int kb = 0; kb < 2; ++kb) {
    const bf16x8 a = ldsA_frag(sT, wv, kb, ln);
    #pragma unroll
    for (int cb = 0; cb < 4; ++cb) {
      const bf16x8 bb = *(const bf16x8*)&g2f[(kb * 4 + cb) * 512 + ln * 8];
      d[cb] = __builtin_amdgcn_mfma_f32_16x16x32_bf16(a, bb, d[cb], 0, 0, 0);
    }
  }
  __syncthreads();
  #pragma unroll
  for (int cb = 0; cb < 4; ++cb)
    #pragma unroll
    for (int r = 0; r < 4; ++r) {
      const int node = rowm + r, feat = 16 * cb + lr;
      const float hv = fmaxf(d[cb][r], 0.f);
      HgTf[(size_t)b * 4096 + bfrag_idx(feat, node, 4)] = f2bf(hv);
      sU[node][feat] = hv;
    }
  __syncthreads();

  // ---- W = Hg @ n2t  [m=64][d=512] -> Wf B-frags (kd = m)
  for (int chk = 0; chk < 4; ++chk) {
    f32x4 aw[8];
    #pragma unroll
    for (int c8 = 0; c8 < 8; ++c8) aw[c8] = (f32x4){0.f, 0.f, 0.f, 0.f};
    #pragma unroll
    for (int kbf = 0; kbf < 2; ++kbf) {
      const bf16x8 a = ldsA_frag(sU, wv, kbf, ln);
      #pragma unroll
      for (int c8 = 0; c8 < 8; ++c8) {
        const bf16x8 bb = *(const bf16x8*)&n2tf[(kbf * 32 + chk * 8 + c8) * 512 + ln * 8];
        aw[c8] = __builtin_amdgcn_mfma_f32_16x16x32_bf16(a, bb, aw[c8], 0, 0, 0);
      }
    }
    #pragma unroll
    for (int c8 = 0; c8 < 8; ++c8)
      #pragma unroll
      for (int r = 0; r < 4; ++r) {
        const int m = 16 * wv + 4 * lq + r;
        const int c = (chk * 8 + c8) * 16 + lr;
        Wf[(size_t)b * 32768 + bfrag_idx(m, c, 32)] = f2bf(aw[c8][r]);
      }
  }
}

// ---------------------------------------------------------------------------
// k_attn: logits(stash)->softmax->back(attn@W)+residual, float4 epilogue
// via wave-private LDS transpose; X residual loads issued before MFMAs.
// ---------------------------------------------------------------------------
__global__ __launch_bounds__(256) void k_attn(
    const float* __restrict__ X, const u16* __restrict__ HgTf,
    const u16* __restrict__ Wf, float* __restrict__ out)
{
  __shared__ __align__(16) u16 sAf[4096];           // 4 waves x 1KB wave-private
  __shared__ __align__(16) float sBo[4][16][68];    // per-wave bounce [16 rows][64+4 cols]
  const int tid = threadIdx.x;
  const int b = blockIdx.x >> 7;
  const int t0 = (blockIdx.x & 127) << 6;
  const float* Xb = X + (size_t)b * N_ * D_;
  float* Ob = out + (size_t)b * N_ * D_;
  const int wv = tid >> 6, ln = tid & 63;
  const int lq = ln >> 4, lr = ln & 15;
  u16* mySf = &sAf[wv * 1024];
  const u16* stash = (const u16*)(out + (size_t)blockIdx.x * 32768);

  // ---- P2: logits = proj @ Hg^T (K=64); proj A-frags read from stash
  f32x4 accL[4];
  #pragma unroll
  for (int cb = 0; cb < 4; ++cb) accL[cb] = (f32x4){0.f, 0.f, 0.f, 0.f};
  #pragma unroll
  for (int kb = 0; kb < 2; ++kb) {
    const bf16x8 a = *(const bf16x8*)&stash[wv * 1024 + kb * 512 + ln * 8];
    #pragma unroll
    for (int cb = 0; cb < 4; ++cb) {
      const bf16x8 bb = *(const bf16x8*)&HgTf[(size_t)b * 4096 + (kb * 4 + cb) * 512 + ln * 8];
      accL[cb] = __builtin_amdgcn_mfma_f32_16x16x32_bf16(a, bb, accL[cb], 0, 0, 0);
    }
  }
  // all stash reads complete before any wave's P7 stores can touch those rows
  __syncthreads();

  // ---- P3: softmax over m in registers
  float attnv[4][4];
  #pragma unroll
  for (int r = 0; r < 4; ++r) {
    const float v0 = accL[0][r], v1 = accL[1][r], v2 = accL[2][r], v3 = accL[3][r];
    float mx = fmaxf(fmaxf(v0, v1), fmaxf(v2, v3));
    mx = fmaxf(mx, __shfl_xor(mx, 1)); mx = fmaxf(mx, __shfl_xor(mx, 2));
    mx = fmaxf(mx, __shfl_xor(mx, 4)); mx = fmaxf(mx, __shfl_xor(mx, 8));
    const float e0 = __expf((v0 - mx) * 0.125f), e1 = __expf((v1 - mx) * 0.125f);
    const float e2 = __expf((v2 - mx) * 0.125f), e3 = __expf((v3 - mx) * 0.125f);
    float sm = (e0 + e1) + (e2 + e3);
    sm += __shfl_xor(sm, 1); sm += __shfl_xor(sm, 2);
    sm += __shfl_xor(sm, 4); sm += __shfl_xor(sm, 8);
    const float inv = 1.f / sm;
    attnv[0][r] = e0 * inv; attnv[1][r] = e1 * inv;
    attnv[2][r] = e2 * inv; attnv[3][r] = e3 * inv;
  }
  // attn D->A bounce, wave-private
  #pragma unroll
  for (int cb = 0; cb < 4; ++cb)
    #pragma unroll
    for (int r = 0; r < 4; ++r) {
      const int idx = (cb >> 1) * 512 + (4 * lq + r + 16 * (lr >> 2)) * 8 +
                      (lr & 3) + 4 * (cb & 1);
      mySf[idx] = f2bf(attnv[cb][r]);
    }

  // ---- P7: back = attn @ W (K=64) + residual, vectorized epilogue
  for (int chk = 0; chk < 4; ++chk) {
    // issue residual X loads early (independent of MFMAs below)
    float4 xres[8];
    #pragma unroll
    for (int h = 0; h < 2; ++h)
      #pragma unroll
      for (int j = 0; j < 4; ++j)
        xres[h * 4 + j] = *(const float4*)(
            Xb + (size_t)(t0 + 16 * wv + 4 * j + lq) * D_ + chk * 128 + h * 64 + 4 * lr);

    f32x4 accB[8];
    #pragma unroll
    for (int c8 = 0; c8 < 8; ++c8) accB[c8] = (f32x4){0.f, 0.f, 0.f, 0.f};
    #pragma unroll
    for (int kb = 0; kb < 2; ++kb) {
      const bf16x8 a = *(const bf16x8*)&mySf[kb * 512 + ln * 8];
      #pragma unroll
      for (int c8 = 0; c8 < 8; ++c8) {
        const bf16x8 bb = *(const bf16x8*)&Wf[(size_t)b * 32768 + (kb * 32 + chk * 8 + c8) * 512 + ln * 8];
        accB[c8] = __builtin_amdgcn_mfma_f32_16x16x32_bf16(a, bb, accB[c8], 0, 0, 0);
      }
    }
    #pragma unroll
    for (int h = 0; h < 2; ++h) {
      #pragma unroll
      for (int c4 = 0; c4 < 4; ++c4)
        #pragma unroll
        for (int r = 0; r < 4; ++r)
          sBo[wv][4 * lq + r][c4 * 16 + lr] = accB[4 * h + c4][r];
      #pragma unroll
      for (int j = 0; j < 4; ++j) {
        const int rloc = 4 * j + lq;
        float4 v = *(const float4*)&sBo[wv][rloc][4 * lr];
        const float4 xv = xres[h * 4 + j];
        v.x += xv.x; v.y += xv.y; v.z += xv.z; v.w += xv.w;
        *(float4*)(Ob + (size_t)(t0 + 16 * wv + rloc) * D_ + chk * 128 + h * 64 + 4 * lr) = v;
      }
    }
  }
}

// ---------------------------------------------------------------------------
extern "C" void kernel_launch(void* const* d_in, const int* in_sizes, int n_in,
                              void* d_out, int out_size, void* d_ws, size_t ws_size,
                              hipStream_t stream)
{
  (void)in_sizes; (void)n_in; (void)out_size; (void)ws_size;
  const float* X   = (const float*)d_in[0];
  const float* W1  = (const float*)d_in[1];
  const float* b1  = (const float*)d_in[2];
  const float* w2  = (const float*)d_in[3];
  const float* b2  = (const float*)d_in[4];
  const float* t2n = (const float*)d_in[5];
  const float* n2t = (const float*)d_in[6];
  const float* g1  = (const float*)d_in[7];
  const float* g2  = (const float*)d_in[8];
  float* out = (float*)d_out;

  char* ws = (char*)d_ws;
  float* scores = (float*)(ws);                  // 256 KB
  u16* t2nf     = (u16*)(ws + 262144);           // 64 KB
  u16* n2tf     = (u16*)(ws + 327680);           // 64 KB
  u16* W1h      = (u16*)(ws + 393216);           // 64 KB
  u16* W1l      = (u16*)(ws + 458752);           // 64 KB
  u16* HgTf     = (u16*)(ws + 524288);           // 64 KB
  u16* g1f      = (u16*)(ws + 589824);           // 8 KB
  u16* g2f      = (u16*)(ws + 598016);           // 8 KB
  int* top_idx  = (int*)(ws + 606208);           // 2 KB
  int* take_k   = (int*)(ws + 608256);           // 32 B
  u16* Wf       = (u16*)(ws + 609280);           // 512 KB

  k_prep<<<64, 256, 0, stream>>>(t2n, n2t, W1, g1, g2, t2nf, n2tf, W1h, W1l, g1f, g2f);
  k_sp<<<1024, 256, 0, stream>>>(X, W1h, W1l, t2nf, b1, w2, b2, scores, out);
  k_select<<<B_, 1024, 0, stream>>>(scores, top_idx, take_k);
  k_graph<<<B_, 256, 0, stream>>>(X, t2nf, n2tf, g1f, g2f, top_idx, take_k, HgTf, Wf);
  k_attn<<<1024, 256, 0, stream>>>(X, HgTf, Wf, out);
}

// Round 10
// 131.358 us; speedup vs baseline: 1.3387x; 1.0069x over previous
//
#include <hip/hip_runtime.h>
#include <hip/hip_bf16.h>

#define B_ 8
#define N_ 8192
#define D_ 512
#define M_ 64

typedef unsigned short u16;
typedef unsigned int u32;
typedef __attribute__((ext_vector_type(8))) short bf16x8;
typedef __attribute__((ext_vector_type(4))) float f32x4;

__device__ __forceinline__ u16 f2bf(float f) {
  u32 u = __float_as_uint(f);
  u += 0x7FFFu + ((u >> 16) & 1u);
  return (u16)(u >> 16);
}
__device__ __forceinline__ float bf2f(u16 h) {
  return __uint_as_float(((u32)h) << 16);
}

// B-fragment index for matrix Mx[kd][c] with N cols: slot mapping shared by A.
__device__ __forceinline__ int bfrag_idx(int kd, int c, int ncols16) {
  int sub = (kd >> 5) * ncols16 + (c >> 4);
  int lane = (c & 15) + 16 * ((kd & 15) >> 2);
  int e = (kd & 3) + 4 * ((kd >> 4) & 1);
  return sub * 512 + lane * 8 + e;
}

// fragment k-slot for (lane, elem) within a 32-k block
__device__ __forceinline__ int kslot(int ln, int e) {
  return (e & 3) + 4 * (ln >> 4) + 16 * (e >> 2);
}

__device__ __forceinline__ bf16x8 pack8(float4 v0, float4 v1) {
  bf16x8 a;
  a[0] = (short)f2bf(v0.x); a[1] = (short)f2bf(v0.y);
  a[2] = (short)f2bf(v0.z); a[3] = (short)f2bf(v0.w);
  a[4] = (short)f2bf(v1.x); a[5] = (short)f2bf(v1.y);
  a[6] = (short)f2bf(v1.z); a[7] = (short)f2bf(v1.w);
  return a;
}

// ---------------------------------------------------------------------------
// k_prep: weights -> bf16 fragment layouts (t2n, n2t, W1 hi/lo, g1, g2)
// ---------------------------------------------------------------------------
__global__ __launch_bounds__(256) void k_prep(
    const float* __restrict__ t2n, const float* __restrict__ n2t,
    const float* __restrict__ W1, const float* __restrict__ g1,
    const float* __restrict__ g2,
    u16* __restrict__ t2nf, u16* __restrict__ n2tf,
    u16* __restrict__ W1h, u16* __restrict__ W1l,
    u16* __restrict__ g1f, u16* __restrict__ g2f)
{
  const int gid = blockIdx.x * 256 + threadIdx.x;
  const int stride = gridDim.x * 256;
  for (int s = gid; s < 512 * 64; s += stride) {
    const int k = s >> 6, c = s & 63;
    const int idx = bfrag_idx(k, c, 4);
    t2nf[idx] = f2bf(t2n[s]);
    const float w = W1[s];
    const u16 wh = f2bf(w);
    W1h[idx] = wh;
    W1l[idx] = f2bf(w - bf2f(wh));
  }
  for (int s = gid; s < 64 * 512; s += stride) {
    const int k = s >> 9, c = s & 511;
    n2tf[bfrag_idx(k, c, 32)] = f2bf(n2t[s]);
  }
  for (int s = gid; s < 4096; s += stride) {
    const int k = s >> 6, c = s & 63;
    g1f[bfrag_idx(k, c, 4)] = f2bf(g1[s]);
    g2f[bfrag_idx(k, c, 4)] = f2bf(g2[s]);
  }
}

// ---------------------------------------------------------------------------
// k_sp: FUSED scores + proj, one X pass.
// B operands staged in DOUBLE-BUFFERED LDS (12 KB x 2): one barrier per
// K-step; global loads issued one full iteration before their ds_write.
// ---------------------------------------------------------------------------
__global__ __launch_bounds__(256, 4) void k_sp(
    const float* __restrict__ X, const u16* __restrict__ W1h,
    const u16* __restrict__ W1l, const u16* __restrict__ t2nf,
    const float* __restrict__ b1, const float* __restrict__ w2,
    const float* __restrict__ b2, float* __restrict__ scores,
    float* __restrict__ outStash)
{
  __shared__ __align__(16) u16 sB[2][6144];  // 2 x 12 frags x 512 u16
  __shared__ __align__(16) u16 sAf[4096];    // proj D->A bounce (post-loop)
  const int tid = threadIdx.x;
  const int t0 = blockIdx.x * 64;
  const int wv = tid >> 6, ln = tid & 63;
  const int lq = ln >> 4, lr = ln & 15;
  u16* mySf = &sAf[wv * 1024];
  const float* xr = X + (size_t)(t0 + 16 * wv + lr) * D_;

  f32x4 acc[4], accP[4];
  #pragma unroll
  for (int cb = 0; cb < 4; ++cb) {
    acc[cb] = (f32x4){0.f, 0.f, 0.f, 0.f};
    accP[cb] = (f32x4){0.f, 0.f, 0.f, 0.f};
  }

  // stage-unit mapping: wave wv stages frags {wv, wv+4, wv+8}
  auto gsrc = [&](int f, int kb) -> const u16* {
    const int cb = f / 3, mat = f % 3;
    const u16* mp = (mat == 0) ? W1h : (mat == 1) ? W1l : t2nf;
    return mp + (kb * 4 + cb) * 512 + ln * 8;
  };

  bf16x8 wr[3];
  // prologue: stage kb=0 directly, then preload kb=1 into regs
  #pragma unroll
  for (int j = 0; j < 3; ++j)
    *(bf16x8*)&sB[0][(j * 4 + wv) * 512 + ln * 8] = *(const bf16x8*)gsrc(j * 4 + wv, 0);
  #pragma unroll
  for (int j = 0; j < 3; ++j) wr[j] = *(const bf16x8*)gsrc(j * 4 + wv, 1);
  float4 va0 = *(const float4*)(xr + 4 * lq);
  float4 va1 = *(const float4*)(xr + 16 + 4 * lq);
  __syncthreads();

  for (int kb = 0; kb < 16; ++kb) {
    const int cur = kb & 1;
    if (kb < 15) {  // write next-step B (loaded one iter ago) into other buffer
      #pragma unroll
      for (int j = 0; j < 3; ++j)
        *(bf16x8*)&sB[cur ^ 1][(j * 4 + wv) * 512 + ln * 8] = wr[j];
    }
    if (kb < 14) {  // issue loads for kb+2; consumed by next iter's ds_write
      #pragma unroll
      for (int j = 0; j < 3; ++j) wr[j] = *(const bf16x8*)gsrc(j * 4 + wv, kb + 2);
    }
    const float4 v0 = va0, v1 = va1;
    if (kb < 15) {
      va0 = *(const float4*)(xr + 32 * (kb + 1) + 4 * lq);
      va1 = *(const float4*)(xr + 32 * (kb + 1) + 16 + 4 * lq);
    }
    const float xs[8] = {v0.x, v0.y, v0.z, v0.w, v1.x, v1.y, v1.z, v1.w};
    bf16x8 ah, al;
    #pragma unroll
    for (int e = 0; e < 8; ++e) {
      const u16 h = f2bf(xs[e]);
      ah[e] = (short)h;
      al[e] = (short)f2bf(xs[e] - bf2f(h));
    }
    #pragma unroll
    for (int cb = 0; cb < 4; ++cb) {
      const bf16x8 bh = *(const bf16x8*)&sB[cur][(cb * 3 + 0) * 512 + ln * 8];
      const bf16x8 bl = *(const bf16x8*)&sB[cur][(cb * 3 + 1) * 512 + ln * 8];
      const bf16x8 bt = *(const bf16x8*)&sB[cur][(cb * 3 + 2) * 512 + ln * 8];
      acc[cb]  = __builtin_amdgcn_mfma_f32_16x16x32_bf16(ah, bh, acc[cb], 0, 0, 0);
      acc[cb]  = __builtin_amdgcn_mfma_f32_16x16x32_bf16(ah, bl, acc[cb], 0, 0, 0);
      acc[cb]  = __builtin_amdgcn_mfma_f32_16x16x32_bf16(al, bh, acc[cb], 0, 0, 0);
      accP[cb] = __builtin_amdgcn_mfma_f32_16x16x32_bf16(ah, bt, accP[cb], 0, 0, 0);
    }
    __syncthreads();  // next buffer populated; current buffer free for reuse
  }

  // ---- scores epilogue
  float b1v[4], w2v[4];
  #pragma unroll
  for (int cb = 0; cb < 4; ++cb) {
    const int col = cb * 16 + lr;
    b1v[cb] = b1[col]; w2v[cb] = w2[col];
  }
  const float b2v = b2[0];
  #pragma unroll
  for (int r = 0; r < 4; ++r) {
    float p = 0.f;
    #pragma unroll
    for (int cb = 0; cb < 4; ++cb) {
      const float h = fmaxf(acc[cb][r] + b1v[cb], 0.f);
      p = fmaf(h, w2v[cb], p);
    }
    p += __shfl_xor(p, 1); p += __shfl_xor(p, 2);
    p += __shfl_xor(p, 4); p += __shfl_xor(p, 8);
    if (lr == 0) scores[t0 + wv * 16 + 4 * lq + r] = p + b2v;
  }

  // ---- proj D->A bounce (wave-private LDS) then coalesced 16B stash
  #pragma unroll
  for (int cb = 0; cb < 4; ++cb)
    #pragma unroll
    for (int r = 0; r < 4; ++r) {
      const int idx = (cb >> 1) * 512 + (4 * lq + r + 16 * (lr >> 2)) * 8 +
                      (lr & 3) + 4 * (cb & 1);
      mySf[idx] = f2bf(accP[cb][r]);
    }
  u16* stash = (u16*)(outStash + (size_t)blockIdx.x * 32768);
  #pragma unroll
  for (int kb2 = 0; kb2 < 2; ++kb2)
    *(bf16x8*)&stash[wv * 1024 + kb2 * 512 + ln * 8] =
        *(const bf16x8*)&mySf[kb2 * 512 + ln * 8];
}

// ---------------------------------------------------------------------------
// fragment loaders from fp32 LDS [64][65]
// ---------------------------------------------------------------------------
__device__ __forceinline__ bf16x8 ldsA_frag(const float (*S)[65], int wv, int kb, int ln) {
  const int lr = ln & 15;
  bf16x8 a;
  #pragma unroll
  for (int e = 0; e < 8; ++e) a[e] = (short)f2bf(S[16 * wv + lr][32 * kb + kslot(ln, e)]);
  return a;
}
__device__ __forceinline__ bf16x8 ldsB_frag(const float (*S)[65], int cb, int kb, int ln) {
  const int lr = ln & 15;
  bf16x8 bb;
  #pragma unroll
  for (int e = 0; e < 8; ++e) bb[e] = (short)f2bf(S[32 * kb + kslot(ln, e)][16 * cb + lr]);
  return bb;
}
__device__ __forceinline__ bf16x8 ldsBT_frag(const float (*S)[65], int cb, int kb, int ln) {
  const int lr = ln & 15;
  bf16x8 bb;
  #pragma unroll
  for (int e = 0; e < 8; ++e) bb[e] = (short)f2bf(S[16 * cb + lr][32 * kb + kslot(ln, e)]);
  return bb;
}

// ---------------------------------------------------------------------------
// k_selgraph: FUSED select + graph (same-block dependency: batch b = block b)
// 1024 threads: select uses all 16 waves; graph MFMA phases guarded tid<256.
// top_idx/take_k live in LDS only.
// ---------------------------------------------------------------------------
__global__ __launch_bounds__(1024) void k_selgraph(
    const float* __restrict__ scores, const float* __restrict__ X,
    const u16* __restrict__ t2nf, const u16* __restrict__ n2tf,
    const u16* __restrict__ g1f, const u16* __restrict__ g2f,
    u16* __restrict__ HgTf, u16* __restrict__ Wf)
{
  __shared__ float sS[N_];
  __shared__ u32 hist[256];
  __shared__ float redf[34];
  __shared__ u32 redu[16];
  __shared__ u32 sPrefix, sRank, sCntA, sCntT;
  __shared__ int candIdx[64];
  __shared__ float candVal[64];
  __shared__ int tieIdx[128];
  __shared__ int sTop[64];
  __shared__ int sTk;
  __shared__ float sH0[64][65];
  __shared__ float sA[64][65];
  __shared__ float sT[64][65];
  __shared__ float sU[64][65];
  __shared__ float sR[64];

  const int b = blockIdx.x, tid = threadIdx.x;
  const int wv = tid >> 6, ln = tid & 63;
  const int lq = ln >> 4, lr = ln & 15;
  const float* s = scores + (size_t)b * N_;

  // ================= SELECT =================
  float sum = 0.f, sq = 0.f;
  for (int i = tid; i < N_; i += 1024) {
    const float v = s[i]; sS[i] = v; sum += v; sq = fmaf(v, v, sq);
  }
  if (tid < 256) hist[tid] = 0;  // pre-clear for the fused count+hist0 pass
  #pragma unroll
  for (int off = 32; off > 0; off >>= 1) {
    sum += __shfl_xor(sum, off);
    sq  += __shfl_xor(sq, off);
  }
  if (ln == 0) { redf[wv] = sum; redf[16 + wv] = sq; }
  __syncthreads();
  if (tid == 0) {
    float tot = 0.f, totq = 0.f;
    #pragma unroll
    for (int w = 0; w < 16; ++w) { tot += redf[w]; totq += redf[16 + w]; }
    const float mean = tot / (float)N_;
    const float var  = totq / (float)N_ - mean * mean;
    redf[32] = mean + 0.5f * sqrtf(fmaxf(var, 0.f));
  }
  __syncthreads();
  const float thr = redf[32];
  // fused: threshold count + pass-0 histogram (independent of thr)
  int c = 0;
  for (int i = tid; i < N_; i += 1024) {
    const float v = sS[i];
    c += (v > thr) ? 1 : 0;
    const u32 u = __float_as_uint(v);
    const u32 key = u ^ ((u32)((int)u >> 31) | 0x80000000u);
    const int bin = (int)(key >> 24);
    unsigned long long act = ~0ull;
    while (act) {
      const int leader = (int)__builtin_ctzll(act);
      const int lbin = __shfl(bin, leader);
      const unsigned long long eq = __ballot(bin == lbin);
      if (ln == leader) atomicAdd(&hist[lbin], (u32)__builtin_popcountll(eq));
      act &= ~eq;
    }
  }
  #pragma unroll
  for (int off = 32; off > 0; off >>= 1) c += __shfl_xor(c, off);
  if (ln == 0) redu[wv] = (u32)c;
  __syncthreads();
  if (tid == 0) {
    int cnt = 0;
    #pragma unroll
    for (int w = 0; w < 16; ++w) cnt += (int)redu[w];
    sTk = (cnt == 0) ? M_ : (cnt < M_ ? cnt : M_);
  }

  u32 prefix = 0, rank = 64, pmask = 0;
  for (int pass = 0; pass < 4; ++pass) {
    const int shift = 24 - 8 * pass;
    if (pass > 0) {
      if (tid < 256) hist[tid] = 0;
      __syncthreads();
      for (int i = tid; i < N_; i += 1024) {
        const u32 u = __float_as_uint(sS[i]);
        const u32 key = u ^ ((u32)((int)u >> 31) | 0x80000000u);
        if ((key & pmask) == prefix) atomicAdd(&hist[(key >> shift) & 255u], 1u);
      }
    }
    __syncthreads();
    if (tid < 64) {
      const u32 h0 = hist[4 * tid], h1 = hist[4 * tid + 1];
      const u32 h2 = hist[4 * tid + 2], h3 = hist[4 * tid + 3];
      const u32 s3 = h3, s2 = h2 + s3, s1 = h1 + s2, s0 = h0 + s1;
      u32 run = s0;
      #pragma unroll
      for (int off = 1; off < 64; off <<= 1) {
        const u32 t = (u32)__shfl_down((int)run, off);
        if (tid + off < 64) run += t;
      }
      const u32 excl = run - s0;
      const u32 c0 = s0 + excl, c1 = s1 + excl, c2 = s2 + excl, c3 = s3 + excl;
      int pick = -1; u32 nxt = 0;
      if (c0 >= rank && c1 < rank)        { pick = 0; nxt = c1; }
      else if (c1 >= rank && c2 < rank)   { pick = 1; nxt = c2; }
      else if (c2 >= rank && c3 < rank)   { pick = 2; nxt = c3; }
      else if (c3 >= rank && excl < rank) { pick = 3; nxt = excl; }
      if (pick >= 0) {
        sPrefix = prefix | ((u32)(4 * tid + pick) << shift);
        sRank = rank - nxt;
      }
    }
    __syncthreads();
    prefix = sPrefix; rank = sRank;
    pmask |= 0xFFu << shift;
    __syncthreads();
  }

  if (tid == 0) { sCntA = 0; sCntT = 0; }
  __syncthreads();
  const u32 pivot = prefix;
  for (int i = tid; i < N_; i += 1024) {
    const u32 u = __float_as_uint(sS[i]);
    const u32 key = u ^ ((u32)((int)u >> 31) | 0x80000000u);
    if (key > pivot) {
      const u32 p = atomicAdd(&sCntA, 1u);
      candIdx[p] = i; candVal[p] = sS[i];
    } else if (key == pivot) {
      const u32 p = atomicAdd(&sCntT, 1u);
      if (p < 128) tieIdx[p] = i;
    }
  }
  __syncthreads();
  if (tid == 0) {
    const int nA = (int)sCntA;
    const int need = 64 - nA;
    int nT = (int)sCntT; if (nT > 128) nT = 128;
    for (int j = 0; j < need; ++j) {
      int bi = 1 << 30, bp = -1;
      for (int q = 0; q < nT; ++q) {
        const int v = tieIdx[q];
        if (v >= 0 && v < bi) { bi = v; bp = q; }
      }
      candIdx[nA + j] = bi; candVal[nA + j] = sS[bi]; tieIdx[bp] = -1;
    }
  }
  __syncthreads();
  if (tid < 64) {
    const float v = candVal[tid]; const int ii = candIdx[tid];
    int rk = 0;
    for (int j = 0; j < 64; ++j) {
      const float vj = candVal[j]; const int ij = candIdx[j];
      rk += (vj > v || (vj == v && ij < ii)) ? 1 : 0;
    }
    sTop[rk] = ii;
  }
  __syncthreads();

  // ================= GRAPH =================
  const int tk = sTk;
  const int rowm = 16 * wv + 4 * lq;
  f32x4 d[4];

  // ---- H0 = gather(X) @ t2n (K=512), masked; depth-3 prefetch ring
  if (tid < 256) {
    const int gidx = sTop[16 * wv + lr];
    const float* xr = X + ((size_t)b * N_ + gidx) * D_;
    #pragma unroll
    for (int cb = 0; cb < 4; ++cb) d[cb] = (f32x4){0.f, 0.f, 0.f, 0.f};
    float4 p0[3], p1[3];
    #pragma unroll
    for (int q = 0; q < 3; ++q) {
      p0[q] = *(const float4*)(xr + 32 * q + 4 * lq);
      p1[q] = *(const float4*)(xr + 32 * q + 16 + 4 * lq);
    }
    #pragma unroll
    for (int kb = 0; kb < 16; ++kb) {
      const int slot = kb % 3;
      const float4 v0 = p0[slot], v1 = p1[slot];
      if (kb + 3 < 16) {
        p0[slot] = *(const float4*)(xr + 32 * (kb + 3) + 4 * lq);
        p1[slot] = *(const float4*)(xr + 32 * (kb + 3) + 16 + 4 * lq);
      }
      const bf16x8 a = pack8(v0, v1);
      #pragma unroll
      for (int cb = 0; cb < 4; ++cb) {
        const bf16x8 bb = *(const bf16x8*)&t2nf[(kb * 4 + cb) * 512 + ln * 8];
        d[cb] = __builtin_amdgcn_mfma_f32_16x16x32_bf16(a, bb, d[cb], 0, 0, 0);
      }
    }
    #pragma unroll
    for (int cb = 0; cb < 4; ++cb)
      #pragma unroll
      for (int r = 0; r < 4; ++r)
        sH0[rowm + r][16 * cb + lr] = (rowm + r < tk) ? d[cb][r] : 0.f;
  }
  __syncthreads();

  // ---- norms -> inverse
  if (tid < 64) {
    float ss = 0.f;
    #pragma unroll
    for (int k = 0; k < 64; ++k) { const float v = sH0[tid][k]; ss = fmaf(v, v, ss); }
    sR[tid] = 1.f / fmaxf(sqrtf(ss), 1e-6f);
  }
  __syncthreads();
  #pragma unroll
  for (int p = 0; p < 4; ++p) {
    const int o = tid + p * 1024;
    sU[o >> 6][o & 63] = sH0[o >> 6][o & 63] * sR[o >> 6];
  }
  __syncthreads();

  // ---- A = relu(Hn @ Hn^T), mask, +diag
  if (tid < 256) {
    #pragma unroll
    for (int cb = 0; cb < 4; ++cb) d[cb] = (f32x4){0.f, 0.f, 0.f, 0.f};
    #pragma unroll
    for (int kb = 0; kb < 2; ++kb) {
      const bf16x8 a = ldsA_frag(sU, wv, kb, ln);
      #pragma unroll
      for (int cb = 0; cb < 4; ++cb)
        d[cb] = __builtin_amdgcn_mfma_f32_16x16x32_bf16(a, ldsBT_frag(sU, cb, kb, ln), d[cb], 0, 0, 0);
    }
  }
  __syncthreads();
  if (tid < 256) {
    #pragma unroll
    for (int cb = 0; cb < 4; ++cb)
      #pragma unroll
      for (int r = 0; r < 4; ++r) {
        const int row = rowm + r, col = 16 * cb + lr;
        float v = fmaxf(d[cb][r], 0.f);
        v = (row < tk && col < tk) ? v : 0.f;
        if (row == col && row < tk) v += 1.f;
        sA[row][col] = v;
      }
  }
  __syncthreads();

  // ---- row-normalize A
  if (tid < 64) {
    float rs = 0.f;
    #pragma unroll
    for (int j = 0; j < 64; ++j) rs += sA[tid][j];
    sR[tid] = 1.f / fmaxf(rs, 1e-6f);
  }
  __syncthreads();
  #pragma unroll
  for (int p = 0; p < 4; ++p) {
    const int o = tid + p * 1024;
    sA[o >> 6][o & 63] *= sR[o >> 6];
  }
  __syncthreads();

  // ---- T = A @ H0
  if (tid < 256) {
    #pragma unroll
    for (int cb = 0; cb < 4; ++cb) d[cb] = (f32x4){0.f, 0.f, 0.f, 0.f};
    #pragma unroll
    for (int kb = 0; kb < 2; ++kb) {
      const bf16x8 a = ldsA_frag(sA, wv, kb, ln);
      #pragma unroll
      for (int cb = 0; cb < 4; ++cb)
        d[cb] = __builtin_amdgcn_mfma_f32_16x16x32_bf16(a, ldsB_frag(sH0, cb, kb, ln), d[cb], 0, 0, 0);
    }
  }
  __syncthreads();
  if (tid < 256) {
    #pragma unroll
    for (int cb = 0; cb < 4; ++cb)
      #pragma unroll
      for (int r = 0; r < 4; ++r) sT[rowm + r][16 * cb + lr] = d[cb][r];
  }
  __syncthreads();

  // ---- X1 = relu(T @ g1)
  if (tid < 256) {
    #pragma unroll
    for (int cb = 0; cb < 4; ++cb) d[cb] = (f32x4){0.f, 0.f, 0.f, 0.f};
    #pragma unroll
    for (int kb = 0; kb < 2; ++kb) {
      const bf16x8 a = ldsA_frag(sT, wv, kb, ln);
      #pragma unroll
      for (int cb = 0; cb < 4; ++cb) {
        const bf16x8 bb = *(const bf16x8*)&g1f[(kb * 4 + cb) * 512 + ln * 8];
        d[cb] = __builtin_amdgcn_mfma_f32_16x16x32_bf16(a, bb, d[cb], 0, 0, 0);
      }
    }
  }
  __syncthreads();
  if (tid < 256) {
    #pragma unroll
    for (int cb = 0; cb < 4; ++cb)
      #pragma unroll
      for (int r = 0; r < 4; ++r) sU[rowm + r][16 * cb + lr] = fmaxf(d[cb][r], 0.f);
  }
  __syncthreads();

  // ---- T2 = A @ X1
  if (tid < 256) {
    #pragma unroll
    for (int cb = 0; cb < 4; ++cb) d[cb] = (f32x4){0.f, 0.f, 0.f, 0.f};
    #pragma unroll
    for (int kb = 0; kb < 2; ++kb) {
      const bf16x8 a = ldsA_frag(sA, wv, kb, ln);
      #pragma unroll
      for (int cb = 0; cb < 4; ++cb)
        d[cb] = __builtin_amdgcn_mfma_f32_16x16x32_bf16(a, ldsB_frag(sU, cb, kb, ln), d[cb], 0, 0, 0);
    }
  }
  __syncthreads();
  if (tid < 256) {
    #pragma unroll
    for (int cb = 0; cb < 4; ++cb)
      #pragma unroll
      for (int r = 0; r < 4; ++r) sT[rowm + r][16 * cb + lr] = d[cb][r];
  }
  __syncthreads();

  // ---- Hg = relu(T2 @ g2) -> HgTf frags + LDS (for W matmul)
  if (tid < 256) {
    #pragma unroll
    for (int cb = 0; cb < 4; ++cb) d[cb] = (f32x4){0.f, 0.f, 0.f, 0.f};
    #pragma unroll
    for (int kb = 0; kb < 2; ++kb) {
      const bf16x8 a = ldsA_frag(sT, wv, kb, ln);
      #pragma unroll
      for (int cb = 0; cb < 4; ++cb) {
        const bf16x8 bb = *(const bf16x8*)&g2f[(kb * 4 + cb) * 512 + ln * 8];
        d[cb] = __builtin_amdgcn_mfma_f32_16x16x32_bf16(a, bb, d[cb], 0, 0, 0);
      }
    }
  }
  __syncthreads();
  if (tid < 256) {
    #pragma unroll
    for (int cb = 0; cb < 4; ++cb)
      #pragma unroll
      for (int r = 0; r < 4; ++r) {
        const int node = rowm + r, feat = 16 * cb + lr;
        const float hv = fmaxf(d[cb][r], 0.f);
        HgTf[(size_t)b * 4096 + bfrag_idx(feat, node, 4)] = f2bf(hv);
        sU[node][feat] = hv;
      }
  }
  __syncthreads();

  // ---- W = Hg @ n2t  [m=64][d=512] -> Wf B-frags (kd = m)
  if (tid < 256) {
    for (int chk = 0; chk < 4; ++chk) {
      f32x4 aw[8];
      #pragma unroll
      for (int c8 = 0; c8 < 8; ++c8) aw[c8] = (f32x4){0.f, 0.f, 0.f, 0.f};
      #pragma unroll
      for (int kbf = 0; kbf < 2; ++kbf) {
        const bf16x8 a = ldsA_frag(sU, wv, kbf, ln);
        #pragma unroll
        for (int c8 = 0; c8 < 8; ++c8) {
          const bf16x8 bb = *(const bf16x8*)&n2tf[(kbf * 32 + chk * 8 + c8) * 512 + ln * 8];
          aw[c8] = __builtin_amdgcn_mfma_f32_16x16x32_bf16(a, bb, aw[c8], 0, 0, 0);
        }
      }
      #pragma unroll
      for (int c8 = 0; c8 < 8; ++c8)
        #pragma unroll
        for (int r = 0; r < 4; ++r) {
          const int m = 16 * wv + 4 * lq + r;
          const int cc = (chk * 8 + c8) * 16 + lr;
          Wf[(size_t)b * 32768 + bfrag_idx(m, cc, 32)] = f2bf(aw[c8][r]);
        }
    }
  }
}

// ---------------------------------------------------------------------------
// k_attn: logits(stash)->softmax->back(attn@W)+residual, float4 epilogue
// ---------------------------------------------------------------------------
__global__ __launch_bounds__(256) void k_attn(
    const float* __restrict__ X, const u16* __restrict__ HgTf,
    const u16* __restrict__ Wf, float* __restrict__ out)
{
  __shared__ __align__(16) u16 sAf[4096];           // 4 waves x 1KB wave-private
  __shared__ __align__(16) float sBo[4][16][68];    // per-wave bounce
  const int tid = threadIdx.x;
  const int b = blockIdx.x >> 7;
  const int t0 = (blockIdx.x & 127) << 6;
  const float* Xb = X + (size_t)b * N_ * D_;
  float* Ob = out + (size_t)b * N_ * D_;
  const int wv = tid >> 6, ln = tid & 63;
  const int lq = ln >> 4, lr = ln & 15;
  u16* mySf = &sAf[wv * 1024];
  const u16* stash = (const u16*)(out + (size_t)blockIdx.x * 32768);

  // ---- P2: logits = proj @ Hg^T (K=64); proj A-frags read from stash
  f32x4 accL[4];
  #pragma unroll
  for (int cb = 0; cb < 4; ++cb) accL[cb] = (f32x4){0.f, 0.f, 0.f, 0.f};
  #pragma unroll
  for (int kb = 0; kb < 2; ++kb) {
    const bf16x8 a = *(const bf16x8*)&stash[wv * 1024 + kb * 512 + ln * 8];
    #pragma unroll
    for (int cb = 0; cb < 4; ++cb) {
      const bf16x8 bb = *(const bf16x8*)&HgTf[(size_t)b * 4096 + (kb * 4 + cb) * 512 + ln * 8];
      accL[cb] = __builtin_amdgcn_mfma_f32_16x16x32_bf16(a, bb, accL[cb], 0, 0, 0);
    }
  }
  __syncthreads();  // stash reads done before P7 stores overwrite those rows

  // ---- P3: softmax over m in registers
  float attnv[4][4];
  #pragma unroll
  for (int r = 0; r < 4; ++r) {
    const float v0 = accL[0][r], v1 = accL[1][r], v2 = accL[2][r], v3 = accL[3][r];
    float mx = fmaxf(fmaxf(v0, v1), fmaxf(v2, v3));
    mx = fmaxf(mx, __shfl_xor(mx, 1)); mx = fmaxf(mx, __shfl_xor(mx, 2));
    mx = fmaxf(mx, __shfl_xor(mx, 4)); mx = fmaxf(mx, __shfl_xor(mx, 8));
    const float e0 = __expf((v0 - mx) * 0.125f), e1 = __expf((v1 - mx) * 0.125f);
    const float e2 = __expf((v2 - mx) * 0.125f), e3 = __expf((v3 - mx) * 0.125f);
    float sm = (e0 + e1) + (e2 + e3);
    sm += __shfl_xor(sm, 1); sm += __shfl_xor(sm, 2);
    sm += __shfl_xor(sm, 4); sm += __shfl_xor(sm, 8);
    const float inv = 1.f / sm;
    attnv[0][r] = e0 * inv; attnv[1][r] = e1 * inv;
    attnv[2][r] = e2 * inv; attnv[3][r] = e3 * inv;
  }
  // attn D->A bounce, wave-private
  #pragma unroll
  for (int cb = 0; cb < 4; ++cb)
    #pragma unroll
    for (int r = 0; r < 4; ++r) {
      const int idx = (cb >> 1) * 512 + (4 * lq + r + 16 * (lr >> 2)) * 8 +
                      (lr & 3) + 4 * (cb & 1);
      mySf[idx] = f2bf(attnv[cb][r]);
    }

  // ---- P7: back = attn @ W (K=64) + residual, vectorized epilogue
  for (int chk = 0; chk < 4; ++chk) {
    float4 xres[8];
    #pragma unroll
    for (int h = 0; h < 2; ++h)
      #pragma unroll
      for (int j = 0; j < 4; ++j)
        xres[h * 4 + j] = *(const float4*)(
            Xb + (size_t)(t0 + 16 * wv + 4 * j + lq) * D_ + chk * 128 + h * 64 + 4 * lr);

    f32x4 accB[8];
    #pragma unroll
    for (int c8 = 0; c8 < 8; ++c8) accB[c8] = (f32x4){0.f, 0.f, 0.f, 0.f};
    #pragma unroll
    for (int kb = 0; kb < 2; ++kb) {
      const bf16x8 a = *(const bf16x8*)&mySf[kb * 512 + ln * 8];
      #pragma unroll
      for (int c8 = 0; c8 < 8; ++c8) {
        const bf16x8 bb = *(const bf16x8*)&Wf[(size_t)b * 32768 + (kb * 32 + chk * 8 + c8) * 512 + ln * 8];
        accB[c8] = __builtin_amdgcn_mfma_f32_16x16x32_bf16(a, bb, accB[c8], 0, 0, 0);
      }
    }
    #pragma unroll
    for (int h = 0; h < 2; ++h) {
      #pragma unroll
      for (int c4 = 0; c4 < 4; ++c4)
        #pragma unroll
        for (int r = 0; r < 4; ++r)
          sBo[wv][4 * lq + r][c4 * 16 + lr] = accB[4 * h + c4][r];
      #pragma unroll
      for (int j = 0; j < 4; ++j) {
        const int rloc = 4 * j + lq;
        float4 v = *(const float4*)&sBo[wv][rloc][4 * lr];
        const float4 xv = xres[h * 4 + j];
        v.x += xv.x; v.y += xv.y; v.z += xv.z; v.w += xv.w;
        *(float4*)(Ob + (size_t)(t0 + 16 * wv + rloc) * D_ + chk * 128 + h * 64 + 4 * lr) = v;
      }
    }
  }
}

// ---------------------------------------------------------------------------
extern "C" void kernel_launch(void* const* d_in, const int* in_sizes, int n_in,
                              void* d_out, int out_size, void* d_ws, size_t ws_size,
                              hipStream_t stream)
{
  (void)in_sizes; (void)n_in; (void)out_size; (void)ws_size;
  const float* X   = (const float*)d_in[0];
  const float* W1  = (const float*)d_in[1];
  const float* b1  = (const float*)d_in[2];
  const float* w2  = (const float*)d_in[3];
  const float* b2  = (const float*)d_in[4];
  const float* t2n = (const float*)d_in[5];
  const float* n2t = (const float*)d_in[6];
  const float* g1  = (const float*)d_in[7];
  const float* g2  = (const float*)d_in[8];
  float* out = (float*)d_out;

  char* ws = (char*)d_ws;
  float* scores = (float*)(ws);                  // 256 KB
  u16* t2nf     = (u16*)(ws + 262144);           // 64 KB
  u16* n2tf     = (u16*)(ws + 327680);           // 64 KB
  u16* W1h      = (u16*)(ws + 393216);           // 64 KB
  u16* W1l      = (u16*)(ws + 458752);           // 64 KB
  u16* HgTf     = (u16*)(ws + 524288);           // 64 KB
  u16* g1f      = (u16*)(ws + 589824);           // 8 KB
  u16* g2f      = (u16*)(ws + 598016);           // 8 KB
  u16* Wf       = (u16*)(ws + 609280);           // 512 KB

  k_prep<<<64, 256, 0, stream>>>(t2n, n2t, W1, g1, g2, t2nf, n2tf, W1h, W1l, g1f, g2f);
  k_sp<<<1024, 256, 0, stream>>>(X, W1h, W1l, t2nf, b1, w2, b2, scores, out);
  k_selgraph<<<B_, 1024, 0, stream>>>(scores, X, t2nf, n2tf, g1f, g2f, HgTf, Wf);
  k_attn<<<1024, 256, 0, stream>>>(X, HgTf, Wf, out);
}

// Round 11
// 127.774 us; speedup vs baseline: 1.3763x; 1.0280x over previous
//
#include <hip/hip_runtime.h>
#include <hip/hip_bf16.h>

#define B_ 8
#define N_ 8192
#define D_ 512
#define M_ 64

typedef unsigned short u16;
typedef unsigned int u32;
typedef __attribute__((ext_vector_type(8))) short bf16x8;
typedef __attribute__((ext_vector_type(4))) float f32x4;

__device__ __forceinline__ u16 f2bf(float f) {
  u32 u = __float_as_uint(f);
  u += 0x7FFFu + ((u >> 16) & 1u);
  return (u16)(u >> 16);
}
__device__ __forceinline__ float bf2f(u16 h) {
  return __uint_as_float(((u32)h) << 16);
}

// B-fragment index for matrix Mx[kd][c] with N cols: slot mapping shared by A.
__device__ __forceinline__ int bfrag_idx(int kd, int c, int ncols16) {
  int sub = (kd >> 5) * ncols16 + (c >> 4);
  int lane = (c & 15) + 16 * ((kd & 15) >> 2);
  int e = (kd & 3) + 4 * ((kd >> 4) & 1);
  return sub * 512 + lane * 8 + e;
}

// fragment k-slot for (lane, elem) within a 32-k block
__device__ __forceinline__ int kslot(int ln, int e) {
  return (e & 3) + 4 * (ln >> 4) + 16 * (e >> 2);
}

__device__ __forceinline__ bf16x8 pack8(float4 v0, float4 v1) {
  bf16x8 a;
  a[0] = (short)f2bf(v0.x); a[1] = (short)f2bf(v0.y);
  a[2] = (short)f2bf(v0.z); a[3] = (short)f2bf(v0.w);
  a[4] = (short)f2bf(v1.x); a[5] = (short)f2bf(v1.y);
  a[6] = (short)f2bf(v1.z); a[7] = (short)f2bf(v1.w);
  return a;
}

// ---------------------------------------------------------------------------
// k_prep: weights -> bf16 fragment layouts (t2n, n2t, W1 hi/lo, g1, g2)
// ---------------------------------------------------------------------------
__global__ __launch_bounds__(256) void k_prep(
    const float* __restrict__ t2n, const float* __restrict__ n2t,
    const float* __restrict__ W1, const float* __restrict__ g1,
    const float* __restrict__ g2,
    u16* __restrict__ t2nf, u16* __restrict__ n2tf,
    u16* __restrict__ W1h, u16* __restrict__ W1l,
    u16* __restrict__ g1f, u16* __restrict__ g2f)
{
  const int gid = blockIdx.x * 256 + threadIdx.x;
  const int stride = gridDim.x * 256;
  for (int s = gid; s < 512 * 64; s += stride) {
    const int k = s >> 6, c = s & 63;
    const int idx = bfrag_idx(k, c, 4);
    t2nf[idx] = f2bf(t2n[s]);
    const float w = W1[s];
    const u16 wh = f2bf(w);
    W1h[idx] = wh;
    W1l[idx] = f2bf(w - bf2f(wh));
  }
  for (int s = gid; s < 64 * 512; s += stride) {
    const int k = s >> 9, c = s & 511;
    n2tf[bfrag_idx(k, c, 32)] = f2bf(n2t[s]);
  }
  for (int s = gid; s < 4096; s += stride) {
    const int k = s >> 6, c = s & 63;
    g1f[bfrag_idx(k, c, 4)] = f2bf(g1[s]);
    g2f[bfrag_idx(k, c, 4)] = f2bf(g2[s]);
  }
}

// ---------------------------------------------------------------------------
// k_sp: FUSED scores + proj, one X pass, double-buffered LDS B-staging.
// ---------------------------------------------------------------------------
__global__ __launch_bounds__(256, 4) void k_sp(
    const float* __restrict__ X, const u16* __restrict__ W1h,
    const u16* __restrict__ W1l, const u16* __restrict__ t2nf,
    const float* __restrict__ b1, const float* __restrict__ w2,
    const float* __restrict__ b2, float* __restrict__ scores,
    float* __restrict__ outStash)
{
  __shared__ __align__(16) u16 sB[2][6144];  // 2 x 12 frags x 512 u16
  __shared__ __align__(16) u16 sAf[4096];    // proj D->A bounce (post-loop)
  const int tid = threadIdx.x;
  const int t0 = blockIdx.x * 64;
  const int wv = tid >> 6, ln = tid & 63;
  const int lq = ln >> 4, lr = ln & 15;
  u16* mySf = &sAf[wv * 1024];
  const float* xr = X + (size_t)(t0 + 16 * wv + lr) * D_;

  f32x4 acc[4], accP[4];
  #pragma unroll
  for (int cb = 0; cb < 4; ++cb) {
    acc[cb] = (f32x4){0.f, 0.f, 0.f, 0.f};
    accP[cb] = (f32x4){0.f, 0.f, 0.f, 0.f};
  }

  auto gsrc = [&](int f, int kb) -> const u16* {
    const int cb = f / 3, mat = f % 3;
    const u16* mp = (mat == 0) ? W1h : (mat == 1) ? W1l : t2nf;
    return mp + (kb * 4 + cb) * 512 + ln * 8;
  };

  bf16x8 wr[3];
  #pragma unroll
  for (int j = 0; j < 3; ++j)
    *(bf16x8*)&sB[0][(j * 4 + wv) * 512 + ln * 8] = *(const bf16x8*)gsrc(j * 4 + wv, 0);
  #pragma unroll
  for (int j = 0; j < 3; ++j) wr[j] = *(const bf16x8*)gsrc(j * 4 + wv, 1);
  float4 va0 = *(const float4*)(xr + 4 * lq);
  float4 va1 = *(const float4*)(xr + 16 + 4 * lq);
  __syncthreads();

  for (int kb = 0; kb < 16; ++kb) {
    const int cur = kb & 1;
    if (kb < 15) {
      #pragma unroll
      for (int j = 0; j < 3; ++j)
        *(bf16x8*)&sB[cur ^ 1][(j * 4 + wv) * 512 + ln * 8] = wr[j];
    }
    if (kb < 14) {
      #pragma unroll
      for (int j = 0; j < 3; ++j) wr[j] = *(const bf16x8*)gsrc(j * 4 + wv, kb + 2);
    }
    const float4 v0 = va0, v1 = va1;
    if (kb < 15) {
      va0 = *(const float4*)(xr + 32 * (kb + 1) + 4 * lq);
      va1 = *(const float4*)(xr + 32 * (kb + 1) + 16 + 4 * lq);
    }
    const float xs[8] = {v0.x, v0.y, v0.z, v0.w, v1.x, v1.y, v1.z, v1.w};
    bf16x8 ah, al;
    #pragma unroll
    for (int e = 0; e < 8; ++e) {
      const u16 h = f2bf(xs[e]);
      ah[e] = (short)h;
      al[e] = (short)f2bf(xs[e] - bf2f(h));
    }
    #pragma unroll
    for (int cb = 0; cb < 4; ++cb) {
      const bf16x8 bh = *(const bf16x8*)&sB[cur][(cb * 3 + 0) * 512 + ln * 8];
      const bf16x8 bl = *(const bf16x8*)&sB[cur][(cb * 3 + 1) * 512 + ln * 8];
      const bf16x8 bt = *(const bf16x8*)&sB[cur][(cb * 3 + 2) * 512 + ln * 8];
      acc[cb]  = __builtin_amdgcn_mfma_f32_16x16x32_bf16(ah, bh, acc[cb], 0, 0, 0);
      acc[cb]  = __builtin_amdgcn_mfma_f32_16x16x32_bf16(ah, bl, acc[cb], 0, 0, 0);
      acc[cb]  = __builtin_amdgcn_mfma_f32_16x16x32_bf16(al, bh, acc[cb], 0, 0, 0);
      accP[cb] = __builtin_amdgcn_mfma_f32_16x16x32_bf16(ah, bt, accP[cb], 0, 0, 0);
    }
    __syncthreads();
  }

  // ---- scores epilogue
  float b1v[4], w2v[4];
  #pragma unroll
  for (int cb = 0; cb < 4; ++cb) {
    const int col = cb * 16 + lr;
    b1v[cb] = b1[col]; w2v[cb] = w2[col];
  }
  const float b2v = b2[0];
  #pragma unroll
  for (int r = 0; r < 4; ++r) {
    float p = 0.f;
    #pragma unroll
    for (int cb = 0; cb < 4; ++cb) {
      const float h = fmaxf(acc[cb][r] + b1v[cb], 0.f);
      p = fmaf(h, w2v[cb], p);
    }
    p += __shfl_xor(p, 1); p += __shfl_xor(p, 2);
    p += __shfl_xor(p, 4); p += __shfl_xor(p, 8);
    if (lr == 0) scores[t0 + wv * 16 + 4 * lq + r] = p + b2v;
  }

  // ---- proj D->A bounce (wave-private LDS) then coalesced 16B stash
  #pragma unroll
  for (int cb = 0; cb < 4; ++cb)
    #pragma unroll
    for (int r = 0; r < 4; ++r) {
      const int idx = (cb >> 1) * 512 + (4 * lq + r + 16 * (lr >> 2)) * 8 +
                      (lr & 3) + 4 * (cb & 1);
      mySf[idx] = f2bf(accP[cb][r]);
    }
  u16* stash = (u16*)(outStash + (size_t)blockIdx.x * 32768);
  #pragma unroll
  for (int kb2 = 0; kb2 < 2; ++kb2)
    *(bf16x8*)&stash[wv * 1024 + kb2 * 512 + ln * 8] =
        *(const bf16x8*)&mySf[kb2 * 512 + ln * 8];
}

// ---------------------------------------------------------------------------
// k_select: REGISTER-RESIDENT exact top-64 radix select. 1024 threads.
// Scores/keys live in VGPRs; all passes scan registers (no LDS score array,
// no ballot loops); parallel 16-lane reductions (no serial tid==0 loops).
// ---------------------------------------------------------------------------
__global__ __launch_bounds__(1024) void k_select(
    const float* __restrict__ scores, int* __restrict__ top_idx,
    int* __restrict__ take_k)
{
  __shared__ u32 hist[256];
  __shared__ float redf[34];
  __shared__ u32 redu[16];
  __shared__ u32 sPrefix, sRank, sCntA, sCntT;
  __shared__ int candIdx[64];
  __shared__ float candVal[64];
  __shared__ int tieIdx[128];
  const int b = blockIdx.x, tid = threadIdx.x;
  const int wv = tid >> 6, ln = tid & 63;
  const float* s = scores + (size_t)b * N_;

  // ---- load 8 elements into registers; stats
  float v[8]; u32 key[8];
  float sum = 0.f, sq = 0.f;
  #pragma unroll
  for (int j = 0; j < 8; ++j) {
    v[j] = s[tid + j * 1024];
    sum += v[j]; sq = fmaf(v[j], v[j], sq);
    const u32 u = __float_as_uint(v[j]);
    key[j] = u ^ ((u32)((int)u >> 31) | 0x80000000u);
  }
  if (tid < 256) hist[tid] = 0;
  #pragma unroll
  for (int off = 32; off > 0; off >>= 1) {
    sum += __shfl_xor(sum, off);
    sq  += __shfl_xor(sq, off);
  }
  if (ln == 0) { redf[wv] = sum; redf[16 + wv] = sq; }
  __syncthreads();
  if (tid < 16) {
    float a = redf[tid], q = redf[16 + tid];
    #pragma unroll
    for (int off = 8; off > 0; off >>= 1) {
      a += __shfl_down(a, off);
      q += __shfl_down(q, off);
    }
    if (tid == 0) {
      const float mean = a / (float)N_;
      const float var = q / (float)N_ - mean * mean;
      redf[32] = mean + 0.5f * sqrtf(fmaxf(var, 0.f));
    }
  }
  __syncthreads();
  const float thr = redf[32];

  // ---- fused: threshold count + pass-0 histogram (both from registers)
  int c = 0;
  #pragma unroll
  for (int j = 0; j < 8; ++j) {
    c += (v[j] > thr) ? 1 : 0;
    atomicAdd(&hist[key[j] >> 24], 1u);
  }
  #pragma unroll
  for (int off = 32; off > 0; off >>= 1) c += __shfl_xor(c, off);
  if (ln == 0) redu[wv] = (u32)c;
  __syncthreads();
  if (tid < 16) {
    u32 a = redu[tid];
    #pragma unroll
    for (int off = 8; off > 0; off >>= 1) a += (u32)__shfl_down((int)a, off);
    if (tid == 0) {
      const int cnt = (int)a;
      take_k[b] = (cnt == 0) ? M_ : (cnt < M_ ? cnt : M_);
    }
  }

  // ---- 4-pass radix: histograms from registers, pick via shfl suffix scan
  u32 prefix = 0, rank = 64, pmask = 0;
  for (int pass = 0; pass < 4; ++pass) {
    const int shift = 24 - 8 * pass;
    if (pass > 0) {
      if (tid < 256) hist[tid] = 0;
      __syncthreads();
      #pragma unroll
      for (int j = 0; j < 8; ++j)
        if ((key[j] & pmask) == prefix) atomicAdd(&hist[(key[j] >> shift) & 255u], 1u);
      __syncthreads();
    }
    if (tid < 64) {
      const u32 h0 = hist[4 * tid], h1 = hist[4 * tid + 1];
      const u32 h2 = hist[4 * tid + 2], h3 = hist[4 * tid + 3];
      const u32 s3 = h3, s2 = h2 + s3, s1 = h1 + s2, s0 = h0 + s1;
      u32 run = s0;
      #pragma unroll
      for (int off = 1; off < 64; off <<= 1) {
        const u32 t = (u32)__shfl_down((int)run, off);
        if (tid + off < 64) run += t;
      }
      const u32 excl = run - s0;
      const u32 c0 = s0 + excl, c1 = s1 + excl, c2 = s2 + excl, c3 = s3 + excl;
      int pick = -1; u32 nxt = 0;
      if (c0 >= rank && c1 < rank)        { pick = 0; nxt = c1; }
      else if (c1 >= rank && c2 < rank)   { pick = 1; nxt = c2; }
      else if (c2 >= rank && c3 < rank)   { pick = 2; nxt = c3; }
      else if (c3 >= rank && excl < rank) { pick = 3; nxt = excl; }
      if (pick >= 0) {
        sPrefix = prefix | ((u32)(4 * tid + pick) << shift);
        sRank = rank - nxt;
      }
    }
    __syncthreads();
    prefix = sPrefix; rank = sRank;
    pmask |= 0xFFu << shift;
    __syncthreads();
  }

  // ---- compaction from registers
  if (tid == 0) { sCntA = 0; sCntT = 0; }
  __syncthreads();
  const u32 pivot = prefix;
  #pragma unroll
  for (int j = 0; j < 8; ++j) {
    if (key[j] > pivot) {
      const u32 p = atomicAdd(&sCntA, 1u);
      candIdx[p] = tid + j * 1024; candVal[p] = v[j];
    } else if (key[j] == pivot) {
      const u32 p = atomicAdd(&sCntT, 1u);
      if (p < 128) tieIdx[p] = tid + j * 1024;
    }
  }
  __syncthreads();
  if (tid == 0) {
    const int nA = (int)sCntA;
    const int need = 64 - nA;
    int nT = (int)sCntT; if (nT > 128) nT = 128;
    const float pv = (pivot & 0x80000000u)
                         ? __uint_as_float(pivot ^ 0x80000000u)
                         : __uint_as_float(~pivot);
    for (int j = 0; j < need; ++j) {
      int bi = 1 << 30, bp = -1;
      for (int q = 0; q < nT; ++q) {
        const int vv = tieIdx[q];
        if (vv >= 0 && vv < bi) { bi = vv; bp = q; }
      }
      candIdx[nA + j] = bi; candVal[nA + j] = pv; tieIdx[bp] = -1;
    }
  }
  __syncthreads();
  if (tid < 64) {
    const float vv = candVal[tid]; const int ii = candIdx[tid];
    int rk = 0;
    for (int j = 0; j < 64; ++j) {
      const float vj = candVal[j]; const int ij = candIdx[j];
      rk += (vj > vv || (vj == vv && ij < ii)) ? 1 : 0;
    }
    top_idx[b * M_ + rk] = ii;
  }
}

// ---------------------------------------------------------------------------
// fragment loaders from fp32 LDS [64][65]
// ---------------------------------------------------------------------------
__device__ __forceinline__ bf16x8 ldsA_frag(const float (*S)[65], int wv, int kb, int ln) {
  const int lr = ln & 15;
  bf16x8 a;
  #pragma unroll
  for (int e = 0; e < 8; ++e) a[e] = (short)f2bf(S[16 * wv + lr][32 * kb + kslot(ln, e)]);
  return a;
}
__device__ __forceinline__ bf16x8 ldsB_frag(const float (*S)[65], int cb, int kb, int ln) {
  const int lr = ln & 15;
  bf16x8 bb;
  #pragma unroll
  for (int e = 0; e < 8; ++e) bb[e] = (short)f2bf(S[32 * kb + kslot(ln, e)][16 * cb + lr]);
  return bb;
}
__device__ __forceinline__ bf16x8 ldsBT_frag(const float (*S)[65], int cb, int kb, int ln) {
  const int lr = ln & 15;
  bf16x8 bb;
  #pragma unroll
  for (int e = 0; e < 8; ++e) bb[e] = (short)f2bf(S[16 * cb + lr][32 * kb + kslot(ln, e)]);
  return bb;
}

// ---------------------------------------------------------------------------
// k_graph: gather + H0 + cosine adjacency + 2-layer GCN + W = Hg@n2t
// ---------------------------------------------------------------------------
__global__ __launch_bounds__(256) void k_graph(
    const float* __restrict__ X, const u16* __restrict__ t2nf,
    const u16* __restrict__ n2tf, const u16* __restrict__ g1f,
    const u16* __restrict__ g2f, const int* __restrict__ top_idx,
    const int* __restrict__ take_k, u16* __restrict__ HgTf,
    u16* __restrict__ Wf)
{
  __shared__ float sH0[64][65];
  __shared__ float sA[64][65];
  __shared__ float sT[64][65];
  __shared__ float sU[64][65];
  __shared__ float sR[64];
  const int b = blockIdx.x, tid = threadIdx.x;
  const int wv = tid >> 6, ln = tid & 63;
  const int lq = ln >> 4, lr = ln & 15;
  const int tk = take_k[b];
  const int rowm = 16 * wv + 4 * lq;

  const int gidx = top_idx[b * M_ + 16 * wv + lr];
  const float* xr = X + ((size_t)b * N_ + gidx) * D_;
  f32x4 d[4];
  #pragma unroll
  for (int cb = 0; cb < 4; ++cb) d[cb] = (f32x4){0.f, 0.f, 0.f, 0.f};
  {
    float4 p0[3], p1[3];
    #pragma unroll
    for (int q = 0; q < 3; ++q) {
      p0[q] = *(const float4*)(xr + 32 * q + 4 * lq);
      p1[q] = *(const float4*)(xr + 32 * q + 16 + 4 * lq);
    }
    #pragma unroll
    for (int kb = 0; kb < 16; ++kb) {
      const int slot = kb % 3;
      const float4 v0 = p0[slot], v1 = p1[slot];
      if (kb + 3 < 16) {
        p0[slot] = *(const float4*)(xr + 32 * (kb + 3) + 4 * lq);
        p1[slot] = *(const float4*)(xr + 32 * (kb + 3) + 16 + 4 * lq);
      }
      const bf16x8 a = pack8(v0, v1);
      #pragma unroll
      for (int cb = 0; cb < 4; ++cb) {
        const bf16x8 bb = *(const bf16x8*)&t2nf[(kb * 4 + cb) * 512 + ln * 8];
        d[cb] = __builtin_amdgcn_mfma_f32_16x16x32_bf16(a, bb, d[cb], 0, 0, 0);
      }
    }
  }
  #pragma unroll
  for (int cb = 0; cb < 4; ++cb)
    #pragma unroll
    for (int r = 0; r < 4; ++r)
      sH0[rowm + r][16 * cb + lr] = (rowm + r < tk) ? d[cb][r] : 0.f;
  __syncthreads();

  if (tid < 64) {
    float ss = 0.f;
    #pragma unroll
    for (int k = 0; k < 64; ++k) { const float vv = sH0[tid][k]; ss = fmaf(vv, vv, ss); }
    sR[tid] = 1.f / fmaxf(sqrtf(ss), 1e-6f);
  }
  __syncthreads();
  #pragma unroll
  for (int p = 0; p < 16; ++p) {
    const int o = tid + p * 256;
    sU[o >> 6][o & 63] = sH0[o >> 6][o & 63] * sR[o >> 6];
  }
  __syncthreads();

  #pragma unroll
  for (int cb = 0; cb < 4; ++cb) d[cb] = (f32x4){0.f, 0.f, 0.f, 0.f};
  #pragma unroll
  for (int kb = 0; kb < 2; ++kb) {
    const bf16x8 a = ldsA_frag(sU, wv, kb, ln);
    #pragma unroll
    for (int cb = 0; cb < 4; ++cb)
      d[cb] = __builtin_amdgcn_mfma_f32_16x16x32_bf16(a, ldsBT_frag(sU, cb, kb, ln), d[cb], 0, 0, 0);
  }
  __syncthreads();
  #pragma unroll
  for (int cb = 0; cb < 4; ++cb)
    #pragma unroll
    for (int r = 0; r < 4; ++r) {
      const int row = rowm + r, col = 16 * cb + lr;
      float ss = fmaxf(d[cb][r], 0.f);
      ss = (row < tk && col < tk) ? ss : 0.f;
      if (row == col && row < tk) ss += 1.f;
      sA[row][col] = ss;
    }
  __syncthreads();

  if (tid < 64) {
    float rs = 0.f;
    #pragma unroll
    for (int j = 0; j < 64; ++j) rs += sA[tid][j];
    sR[tid] = 1.f / fmaxf(rs, 1e-6f);
  }
  __syncthreads();
  #pragma unroll
  for (int p = 0; p < 16; ++p) {
    const int o = tid + p * 256;
    sA[o >> 6][o & 63] *= sR[o >> 6];
  }
  __syncthreads();

  #pragma unroll
  for (int cb = 0; cb < 4; ++cb) d[cb] = (f32x4){0.f, 0.f, 0.f, 0.f};
  #pragma unroll
  for (int kb = 0; kb < 2; ++kb) {
    const bf16x8 a = ldsA_frag(sA, wv, kb, ln);
    #pragma unroll
    for (int cb = 0; cb < 4; ++cb)
      d[cb] = __builtin_amdgcn_mfma_f32_16x16x32_bf16(a, ldsB_frag(sH0, cb, kb, ln), d[cb], 0, 0, 0);
  }
  __syncthreads();
  #pragma unroll
  for (int cb = 0; cb < 4; ++cb)
    #pragma unroll
    for (int r = 0; r < 4; ++r) sT[rowm + r][16 * cb + lr] = d[cb][r];
  __syncthreads();

  #pragma unroll
  for (int cb = 0; cb < 4; ++cb) d[cb] = (f32x4){0.f, 0.f, 0.f, 0.f};
  #pragma unroll
  for (int kb = 0; kb < 2; ++kb) {
    const bf16x8 a = ldsA_frag(sT, wv, kb, ln);
    #pragma unroll
    for (int cb = 0; cb < 4; ++cb) {
      const bf16x8 bb = *(const bf16x8*)&g1f[(kb * 4 + cb) * 512 + ln * 8];
      d[cb] = __builtin_amdgcn_mfma_f32_16x16x32_bf16(a, bb, d[cb], 0, 0, 0);
    }
  }
  __syncthreads();
  #pragma unroll
  for (int cb = 0; cb < 4; ++cb)
    #pragma unroll
    for (int r = 0; r < 4; ++r) sU[rowm + r][16 * cb + lr] = fmaxf(d[cb][r], 0.f);
  __syncthreads();

  #pragma unroll
  for (int cb = 0; cb < 4; ++cb) d[cb] = (f32x4){0.f, 0.f, 0.f, 0.f};
  #pragma unroll
  for (int kb = 0; kb < 2; ++kb) {
    const bf16x8 a = ldsA_frag(sA, wv, kb, ln);
    #pragma unroll
    for (int cb = 0; cb < 4; ++cb)
      d[cb] = __builtin_amdgcn_mfma_f32_16x16x32_bf16(a, ldsB_frag(sU, cb, kb, ln), d[cb], 0, 0, 0);
  }
  __syncthreads();
  #pragma unroll
  for (int cb = 0; cb < 4; ++cb)
    #pragma unroll
    for (int r = 0; r < 4; ++r) sT[rowm + r][16 * cb + lr] = d[cb][r];
  __syncthreads();

  #pragma unroll
  for (int cb = 0; cb < 4; ++cb) d[cb] = (f32x4){0.f, 0.f, 0.f, 0.f};
  #pragma unroll
  for (int kb = 0; kb < 2; ++kb) {
    const bf16x8 a = ldsA_frag(sT, wv, kb, ln);
    #pragma unroll
    for (int cb = 0; cb < 4; ++cb) {
      const bf16x8 bb = *(const bf16x8*)&g2f[(kb * 4 + cb) * 512 + ln * 8];
      d[cb] = __builtin_amdgcn_mfma_f32_16x16x32_bf16(a, bb, d[cb], 0, 0, 0);
    }
  }
  __syncthreads();
  #pragma unroll
  for (int cb = 0; cb < 4; ++cb)
    #pragma unroll
    for (int r = 0; r < 4; ++r) {
      const int node = rowm + r, feat = 16 * cb + lr;
      const float hv = fmaxf(d[cb][r], 0.f);
      HgTf[(size_t)b * 4096 + bfrag_idx(feat, node, 4)] = f2bf(hv);
      sU[node][feat] = hv;
    }
  __syncthreads();

  for (int chk = 0; chk < 4; ++chk) {
    f32x4 aw[8];
    #pragma unroll
    for (int c8 = 0; c8 < 8; ++c8) aw[c8] = (f32x4){0.f, 0.f, 0.f, 0.f};
    #pragma unroll
    for (int kbf = 0; kbf < 2; ++kbf) {
      const bf16x8 a = ldsA_frag(sU, wv, kbf, ln);
      #pragma unroll
      for (int c8 = 0; c8 < 8; ++c8) {
        const bf16x8 bb = *(const bf16x8*)&n2tf[(kbf * 32 + chk * 8 + c8) * 512 + ln * 8];
        aw[c8] = __builtin_amdgcn_mfma_f32_16x16x32_bf16(a, bb, aw[c8], 0, 0, 0);
      }
    }
    #pragma unroll
    for (int c8 = 0; c8 < 8; ++c8)
      #pragma unroll
      for (int r = 0; r < 4; ++r) {
        const int m = 16 * wv + 4 * lq + r;
        const int cc = (chk * 8 + c8) * 16 + lr;
        Wf[(size_t)b * 32768 + bfrag_idx(m, cc, 32)] = f2bf(aw[c8][r]);
      }
  }
}

// ---------------------------------------------------------------------------
// k_attn: logits(stash)->softmax->back(attn@W)+residual, float4 epilogue
// ---------------------------------------------------------------------------
__global__ __launch_bounds__(256) void k_attn(
    const float* __restrict__ X, const u16* __restrict__ HgTf,
    const u16* __restrict__ Wf, float* __restrict__ out)
{
  __shared__ __align__(16) u16 sAf[4096];
  __shared__ __align__(16) float sBo[4][16][68];
  const int tid = threadIdx.x;
  const int b = blockIdx.x >> 7;
  const int t0 = (blockIdx.x & 127) << 6;
  const float* Xb = X + (size_t)b * N_ * D_;
  float* Ob = out + (size_t)b * N_ * D_;
  const int wv = tid >> 6, ln = tid & 63;
  const int lq = ln >> 4, lr = ln & 15;
  u16* mySf = &sAf[wv * 1024];
  const u16* stash = (const u16*)(out + (size_t)blockIdx.x * 32768);

  f32x4 accL[4];
  #pragma unroll
  for (int cb = 0; cb < 4; ++cb) accL[cb] = (f32x4){0.f, 0.f, 0.f, 0.f};
  #pragma unroll
  for (int kb = 0; kb < 2; ++kb) {
    const bf16x8 a = *(const bf16x8*)&stash[wv * 1024 + kb * 512 + ln * 8];
    #pragma unroll
    for (int cb = 0; cb < 4; ++cb) {
      const bf16x8 bb = *(const bf16x8*)&HgTf[(size_t)b * 4096 + (kb * 4 + cb) * 512 + ln * 8];
      accL[cb] = __builtin_amdgcn_mfma_f32_16x16x32_bf16(a, bb, accL[cb], 0, 0, 0);
    }
  }
  __syncthreads();

  float attnv[4][4];
  #pragma unroll
  for (int r = 0; r < 4; ++r) {
    const float v0 = accL[0][r], v1 = accL[1][r], v2 = accL[2][r], v3 = accL[3][r];
    float mx = fmaxf(fmaxf(v0, v1), fmaxf(v2, v3));
    mx = fmaxf(mx, __shfl_xor(mx, 1)); mx = fmaxf(mx, __shfl_xor(mx, 2));
    mx = fmaxf(mx, __shfl_xor(mx, 4)); mx = fmaxf(mx, __shfl_xor(mx, 8));
    const float e0 = __expf((v0 - mx) * 0.125f), e1 = __expf((v1 - mx) * 0.125f);
    const float e2 = __expf((v2 - mx) * 0.125f), e3 = __expf((v3 - mx) * 0.125f);
    float sm = (e0 + e1) + (e2 + e3);
    sm += __shfl_xor(sm, 1); sm += __shfl_xor(sm, 2);
    sm += __shfl_xor(sm, 4); sm += __shfl_xor(sm, 8);
    const float inv = 1.f / sm;
    attnv[0][r] = e0 * inv; attnv[1][r] = e1 * inv;
    attnv[2][r] = e2 * inv; attnv[3][r] = e3 * inv;
  }
  #pragma unroll
  for (int cb = 0; cb < 4; ++cb)
    #pragma unroll
    for (int r = 0; r < 4; ++r) {
      const int idx = (cb >> 1) * 512 + (4 * lq + r + 16 * (lr >> 2)) * 8 +
                      (lr & 3) + 4 * (cb & 1);
      mySf[idx] = f2bf(attnv[cb][r]);
    }

  for (int chk = 0; chk < 4; ++chk) {
    float4 xres[8];
    #pragma unroll
    for (int h = 0; h < 2; ++h)
      #pragma unroll
      for (int j = 0; j < 4; ++j)
        xres[h * 4 + j] = *(const float4*)(
            Xb + (size_t)(t0 + 16 * wv + 4 * j + lq) * D_ + chk * 128 + h * 64 + 4 * lr);

    f32x4 accB[8];
    #pragma unroll
    for (int c8 = 0; c8 < 8; ++c8) accB[c8] = (f32x4){0.f, 0.f, 0.f, 0.f};
    #pragma unroll
    for (int kb = 0; kb < 2; ++kb) {
      const bf16x8 a = *(const bf16x8*)&mySf[kb * 512 + ln * 8];
      #pragma unroll
      for (int c8 = 0; c8 < 8; ++c8) {
        const bf16x8 bb = *(const bf16x8*)&Wf[(size_t)b * 32768 + (kb * 32 + chk * 8 + c8) * 512 + ln * 8];
        accB[c8] = __builtin_amdgcn_mfma_f32_16x16x32_bf16(a, bb, accB[c8], 0, 0, 0);
      }
    }
    #pragma unroll
    for (int h = 0; h < 2; ++h) {
      #pragma unroll
      for (int c4 = 0; c4 < 4; ++c4)
        #pragma unroll
        for (int r = 0; r < 4; ++r)
          sBo[wv][4 * lq + r][c4 * 16 + lr] = accB[4 * h + c4][r];
      #pragma unroll
      for (int j = 0; j < 4; ++j) {
        const int rloc = 4 * j + lq;
        float4 vv = *(const float4*)&sBo[wv][rloc][4 * lr];
        const float4 xv = xres[h * 4 + j];
        vv.x += xv.x; vv.y += xv.y; vv.z += xv.z; vv.w += xv.w;
        *(float4*)(Ob + (size_t)(t0 + 16 * wv + rloc) * D_ + chk * 128 + h * 64 + 4 * lr) = vv;
      }
    }
  }
}

// ---------------------------------------------------------------------------
extern "C" void kernel_launch(void* const* d_in, const int* in_sizes, int n_in,
                              void* d_out, int out_size, void* d_ws, size_t ws_size,
                              hipStream_t stream)
{
  (void)in_sizes; (void)n_in; (void)out_size; (void)ws_size;
  const float* X   = (const float*)d_in[0];
  const float* W1  = (const float*)d_in[1];
  const float* b1  = (const float*)d_in[2];
  const float* w2  = (const float*)d_in[3];
  const float* b2  = (const float*)d_in[4];
  const float* t2n = (const float*)d_in[5];
  const float* n2t = (const float*)d_in[6];
  const float* g1  = (const float*)d_in[7];
  const float* g2  = (const float*)d_in[8];
  float* out = (float*)d_out;

  char* ws = (char*)d_ws;
  float* scores = (float*)(ws);                  // 256 KB
  u16* t2nf     = (u16*)(ws + 262144);           // 64 KB
  u16* n2tf     = (u16*)(ws + 327680);           // 64 KB
  u16* W1h      = (u16*)(ws + 393216);           // 64 KB
  u16* W1l      = (u16*)(ws + 458752);           // 64 KB
  u16* HgTf     = (u16*)(ws + 524288);           // 64 KB
  u16* g1f      = (u16*)(ws + 589824);           // 8 KB
  u16* g2f      = (u16*)(ws + 598016);           // 8 KB
  int* top_idx  = (int*)(ws + 606208);           // 2 KB
  int* take_k   = (int*)(ws + 608256);           // 32 B
  u16* Wf       = (u16*)(ws + 609280);           // 512 KB

  k_prep<<<64, 256, 0, stream>>>(t2n, n2t, W1, g1, g2, t2nf, n2tf, W1h, W1l, g1f, g2f);
  k_sp<<<1024, 256, 0, stream>>>(X, W1h, W1l, t2nf, b1, w2, b2, scores, out);
  k_select<<<B_, 1024, 0, stream>>>(scores, top_idx, take_k);
  k_graph<<<B_, 256, 0, stream>>>(X, t2nf, n2tf, g1f, g2f, top_idx, take_k, HgTf, Wf);
  k_attn<<<1024, 256, 0, stream>>>(X, HgTf, Wf, out);
}